// Round 11
// baseline (466.000 us; speedup 1.0000x reference)
//
#include <hip/hip_runtime.h>
#include <math.h>
#include <stdint.h>

typedef __bf16 bf16x8_t __attribute__((ext_vector_type(8)));
typedef float  f32x4_t  __attribute__((ext_vector_type(4)));
typedef unsigned short u16;

// ---- helpers -------------------------------------------------------------

__device__ __forceinline__ u16 f2bf(float f) {
  unsigned u = __float_as_uint(f);
  u += 0x7FFFu + ((u >> 16) & 1u);
  return (u16)(u >> 16);
}

__device__ __forceinline__ void gload_lds16(const u16* gsrc, u16* ldst) {
  // async global->LDS, 16B per lane; LDS dest = wave-uniform base + lane*16
  __builtin_amdgcn_global_load_lds(
      (__attribute__((address_space(1))) void*)(const_cast<u16*>(gsrc)),
      (__attribute__((address_space(3))) void*)(ldst),
      16, 0, 0);
}

// XOR swizzle for 128B rows (64 bf16): byte ^= ((row&7)<<4) == elem ^= ((row&7)<<3)
__device__ __forceinline__ int sw8(int row, int e) { return e ^ ((row & 7) << 3); }

__device__ __forceinline__ void store_out(float* C, long idx, float v) { C[idx] = v; }
__device__ __forceinline__ void store_out(u16* C, long idx, float v) { C[idx] = f2bf(v); }

__device__ __forceinline__ float alibi_slope(int h, int H) {
  int cp2 = 1, lg = 0;
  while (cp2 * 2 <= H) { cp2 *= 2; lg++; }
  if (h < cp2) {
    double e = exp2((double)-(lg - 3));
    return (float)exp2(-e * (double)(h + 1));
  } else {
    double e = exp2((double)-(lg + 1 - 3));
    return (float)exp2(-e * (double)(2 * (h - cp2) + 1));
  }
}

#define FENCE() asm volatile("" ::: "memory")
#define BARRIER() do { FENCE(); __builtin_amdgcn_s_barrier(); \
                       __builtin_amdgcn_sched_barrier(0); FENCE(); } while (0)
#define WAITLGKM() do { asm volatile("s_waitcnt lgkmcnt(0)" ::: "memory"); \
                        __builtin_amdgcn_sched_barrier(0); } while (0)

// ---- elementwise cast f32 -> bf16 ---------------------------------------

__global__ __launch_bounds__(256) void k_cast_bf16(const float* __restrict__ in,
                                                   u16* __restrict__ out, long n) {
  long i = ((long)blockIdx.x * 256 + threadIdx.x) * 4;
  if (i + 3 < n) {
    float4 v = *reinterpret_cast<const float4*>(in + i);
    ushort4 o;
    o.x = f2bf(v.x); o.y = f2bf(v.y); o.z = f2bf(v.z); o.w = f2bf(v.w);
    *reinterpret_cast<ushort4*>(out + i) = o;
  }
}

// ---- transpose + cast: out[z][c][r] = bf16(in[z][r][c]) ------------------

__global__ __launch_bounds__(256) void k_transpose_cast(const float* __restrict__ in,
                                                        u16* __restrict__ out,
                                                        int R, int C) {
  __shared__ float tile[32][33];
  const float* inz = in + (long)blockIdx.z * R * C;
  u16* outz = out + (long)blockIdx.z * R * C;
  const int tx = threadIdx.x & 31, ty = threadIdx.x >> 5;
  const int r0 = blockIdx.y * 32, c0 = blockIdx.x * 32;
#pragma unroll
  for (int i = 0; i < 4; ++i)
    tile[ty + i * 8][tx] = inz[(long)(r0 + ty + i * 8) * C + c0 + tx];
  __syncthreads();
#pragma unroll
  for (int i = 0; i < 4; ++i)
    outz[(long)(c0 + ty + i * 8) * R + r0 + tx] = f2bf(tile[tx][ty + i * 8]);
}

// ---- per-(b,h) transpose of V: [S,Dh slice of D] -> Vt[bh][Dh][S] --------

__global__ __launch_bounds__(256) void k_transpose_v(const u16* __restrict__ V,
                                                     u16* __restrict__ Vt,
                                                     int S, int D, int Dh, int H) {
  __shared__ u16 tile[32][33];
  const int bh = blockIdx.z, b = bh / H, h = bh % H;
  const int tx = threadIdx.x & 31, ty = threadIdx.x >> 5;
  const int s0 = blockIdx.x * 32, d0 = blockIdx.y * 32;
  const u16* vin = V + (long)b * S * D + (long)h * Dh;
#pragma unroll
  for (int i = 0; i < 4; ++i)
    tile[ty + i * 8][tx] = vin[(long)(s0 + ty + i * 8) * D + d0 + tx];
  __syncthreads();
  u16* vout = Vt + (long)bh * Dh * S;
#pragma unroll
  for (int i = 0; i < 4; ++i)
    vout[(long)(d0 + ty + i * 8) * S + s0 + tx] = tile[tx][ty + i * 8];
}

// ---- staging helpers (linear LDS dest + inverse-swizzled global source) --

__device__ __forceinline__ void stage16(const u16* __restrict__ g, long grow0, int K,
                                        int kt, int lr0, u16 (*lds)[64], int lane) {
  const int e = (lane & 7) * 8;
#pragma unroll
  for (int i = 0; i < 2; ++i) {
    const int r = lr0 + i * 8 + (lane >> 3);
    gload_lds16(g + (grow0 + r) * (long)K + kt + (e ^ ((r & 7) << 3)), &lds[lr0 + i * 8][0]);
  }
}

__device__ __forceinline__ void stage8(const u16* __restrict__ g, long grow0, int K,
                                       int kt, int lr0, u16 (*lds)[64], int lane) {
  const int e = (lane & 7) * 8;
  const int r = lr0 + (lane >> 3);
  gload_lds16(g + (grow0 + r) * (long)K + kt + (e ^ ((r & 7) << 3)), &lds[lr0][0]);
}

// ---- 256x384 6-phase bf16 GEMM (QKV: grid 16x16 = 256 blocks = 1 round) --
// C[M,N] = A[M,K]*Bt[N,K]^T. 8 waves 2Mx4N, wave tile 128x96 (acc[8][6]).
// LDS 128KB: B double-buffered 2x[384][64] (96K), A single-buffered
// [256][64] (32K). Per K-tile 6 phases x 16 MFMA; stage B(t+1) parts at
// ph1-3 (3-5 phase lag), A(t+1) at ph5 (A reads end at ph4 barrier ->
// overwrite race-free); one vmcnt(0) at ph6-end (all drained loads are
// >=1 phase old). qs scales cols < 2048 (Q prescale).

template <typename OUT_T>
__global__ __launch_bounds__(512, 2) void k_gemm384(const u16* __restrict__ A,
                                                    const u16* __restrict__ Bt,
                                                    OUT_T* __restrict__ Cb,
                                                    int M, int N, int K, long matStride,
                                                    float qs) {
  __shared__ u16 As[256][64];       // 32KB single-buffered
  __shared__ u16 Bs[2][384][64];    // 96KB double-buffered

  const int tid = threadIdx.x, wid = tid >> 6, lane = tid & 63;
  const int wr = wid >> 2, wc = wid & 3;
  const int frow = lane & 15, fk8 = (lane >> 4) * 8;
  const int orow = (lane >> 4) * 4, ocol = lane & 15;

  // T1: bijective XCD-aware swizzle (nwg = 256 -> exact)
  const int nwg = gridDim.x * gridDim.y;
  const int orig = blockIdx.y * gridDim.x + blockIdx.x;
  const int q = nwg >> 3, rr = nwg & 7;
  const int xcd = orig & 7, sl = orig >> 3;
  const int wg = (xcd < rr ? xcd * (q + 1) : rr * (q + 1) + (xcd - rr) * q) + sl;
  const int by = wg / gridDim.x, bx = wg % gridDim.x;

  const long abase = (long)by * 256, bbase = (long)bx * 384;

  const int bg0 = wid * 48;   // B: each wave stages 48 rows (3 x stage16)
  const int ag0 = wid * 32;   // A: each wave stages 32 rows (2 x stage16)

  f32x4_t acc[8][6];
#pragma unroll
  for (int m = 0; m < 8; ++m)
#pragma unroll
    for (int n = 0; n < 6; ++n)
#pragma unroll
      for (int r = 0; r < 4; ++r) acc[m][n][r] = 0.f;

  const int nt = K >> 6;

  // prologue: tile 0
  stage16(Bt, bbase, K, 0, bg0, Bs[0], lane);
  stage16(Bt, bbase, K, 0, bg0 + 16, Bs[0], lane);
  stage16(Bt, bbase, K, 0, bg0 + 32, Bs[0], lane);
  stage16(A, abase, K, 0, ag0, As, lane);
  stage16(A, abase, K, 0, ag0 + 16, As, lane);
  asm volatile("s_waitcnt vmcnt(0)" ::: "memory");
  BARRIER();

  bf16x8_t afr[4][2], bfr[6][2];
  int cur = 0;

  for (int t = 0; t < nt; ++t) {
    const int ktn = (t + 1) << 6;
    const bool hn = (t + 1 < nt);
    const int nb = cur ^ 1;

    // ---- phase 1: (m0-3, n0-1); read a0 + b01; stage B-part1(t+1)
#pragma unroll
    for (int m = 0; m < 4; ++m) {
      const int r = wr * 128 + m * 16 + frow;
      afr[m][0] = *reinterpret_cast<const bf16x8_t*>(&As[r][sw8(r, fk8)]);
      afr[m][1] = *reinterpret_cast<const bf16x8_t*>(&As[r][sw8(r, 32 + fk8)]);
    }
#pragma unroll
    for (int n = 0; n < 2; ++n) {
      const int r = wc * 96 + n * 16 + frow;
      bfr[n][0] = *reinterpret_cast<const bf16x8_t*>(&Bs[cur][r][sw8(r, fk8)]);
      bfr[n][1] = *reinterpret_cast<const bf16x8_t*>(&Bs[cur][r][sw8(r, 32 + fk8)]);
    }
    if (hn) stage16(Bt, bbase, K, ktn, bg0, Bs[nb], lane);
    BARRIER();
    WAITLGKM();
    __builtin_amdgcn_s_setprio(1);
#pragma unroll
    for (int m = 0; m < 4; ++m)
#pragma unroll
      for (int n = 0; n < 2; ++n) {
        acc[m][n] = __builtin_amdgcn_mfma_f32_16x16x32_bf16(afr[m][0], bfr[n][0], acc[m][n], 0, 0, 0);
        acc[m][n] = __builtin_amdgcn_mfma_f32_16x16x32_bf16(afr[m][1], bfr[n][1], acc[m][n], 0, 0, 0);
      }
    __builtin_amdgcn_s_setprio(0);
    BARRIER();

    // ---- phase 2: (m0-3, n2-3); read b23; stage B-part2(t+1)
#pragma unroll
    for (int n = 2; n < 4; ++n) {
      const int r = wc * 96 + n * 16 + frow;
      bfr[n][0] = *reinterpret_cast<const bf16x8_t*>(&Bs[cur][r][sw8(r, fk8)]);
      bfr[n][1] = *reinterpret_cast<const bf16x8_t*>(&Bs[cur][r][sw8(r, 32 + fk8)]);
    }
    if (hn) stage16(Bt, bbase, K, ktn, bg0 + 16, Bs[nb], lane);
    BARRIER();
    WAITLGKM();
    __builtin_amdgcn_s_setprio(1);
#pragma unroll
    for (int m = 0; m < 4; ++m)
#pragma unroll
      for (int n = 2; n < 4; ++n) {
        acc[m][n] = __builtin_amdgcn_mfma_f32_16x16x32_bf16(afr[m][0], bfr[n][0], acc[m][n], 0, 0, 0);
        acc[m][n] = __builtin_amdgcn_mfma_f32_16x16x32_bf16(afr[m][1], bfr[n][1], acc[m][n], 0, 0, 0);
      }
    __builtin_amdgcn_s_setprio(0);
    BARRIER();

    // ---- phase 3: (m0-3, n4-5); read b45; stage B-part3(t+1)
#pragma unroll
    for (int n = 4; n < 6; ++n) {
      const int r = wc * 96 + n * 16 + frow;
      bfr[n][0] = *reinterpret_cast<const bf16x8_t*>(&Bs[cur][r][sw8(r, fk8)]);
      bfr[n][1] = *reinterpret_cast<const bf16x8_t*>(&Bs[cur][r][sw8(r, 32 + fk8)]);
    }
    if (hn) stage16(Bt, bbase, K, ktn, bg0 + 32, Bs[nb], lane);
    BARRIER();
    WAITLGKM();
    __builtin_amdgcn_s_setprio(1);
#pragma unroll
    for (int m = 0; m < 4; ++m)
#pragma unroll
      for (int n = 4; n < 6; ++n) {
        acc[m][n] = __builtin_amdgcn_mfma_f32_16x16x32_bf16(afr[m][0], bfr[n][0], acc[m][n], 0, 0, 0);
        acc[m][n] = __builtin_amdgcn_mfma_f32_16x16x32_bf16(afr[m][1], bfr[n][1], acc[m][n], 0, 0, 0);
      }
    __builtin_amdgcn_s_setprio(0);
    BARRIER();

    // ---- phase 4: (m4-7, n0-1); read a1 (last A reads of tile t)
#pragma unroll
    for (int m = 0; m < 4; ++m) {
      const int r = wr * 128 + 64 + m * 16 + frow;
      afr[m][0] = *reinterpret_cast<const bf16x8_t*>(&As[r][sw8(r, fk8)]);
      afr[m][1] = *reinterpret_cast<const bf16x8_t*>(&As[r][sw8(r, 32 + fk8)]);
    }
    BARRIER();
    WAITLGKM();
    __builtin_amdgcn_s_setprio(1);
#pragma unroll
    for (int m = 0; m < 4; ++m)
#pragma unroll
      for (int n = 0; n < 2; ++n) {
        acc[4 + m][n] = __builtin_amdgcn_mfma_f32_16x16x32_bf16(afr[m][0], bfr[n][0], acc[4 + m][n], 0, 0, 0);
        acc[4 + m][n] = __builtin_amdgcn_mfma_f32_16x16x32_bf16(afr[m][1], bfr[n][1], acc[4 + m][n], 0, 0, 0);
      }
    __builtin_amdgcn_s_setprio(0);
    BARRIER();

    // ---- phase 5: (m4-7, n2-3); stage A(t+1) (safe: A reads ended ph4)
    if (hn) {
      stage16(A, abase, K, ktn, ag0, As, lane);
      stage16(A, abase, K, ktn, ag0 + 16, As, lane);
    }
    __builtin_amdgcn_s_setprio(1);
#pragma unroll
    for (int m = 0; m < 4; ++m)
#pragma unroll
      for (int n = 2; n < 4; ++n) {
        acc[4 + m][n] = __builtin_amdgcn_mfma_f32_16x16x32_bf16(afr[m][0], bfr[n][0], acc[4 + m][n], 0, 0, 0);
        acc[4 + m][n] = __builtin_amdgcn_mfma_f32_16x16x32_bf16(afr[m][1], bfr[n][1], acc[4 + m][n], 0, 0, 0);
      }
    __builtin_amdgcn_s_setprio(0);
    BARRIER();

    // ---- phase 6: (m4-7, n4-5); tile-boundary drain
    __builtin_amdgcn_s_setprio(1);
#pragma unroll
    for (int m = 0; m < 4; ++m)
#pragma unroll
      for (int n = 4; n < 6; ++n) {
        acc[4 + m][n] = __builtin_amdgcn_mfma_f32_16x16x32_bf16(afr[m][0], bfr[n][0], acc[4 + m][n], 0, 0, 0);
        acc[4 + m][n] = __builtin_amdgcn_mfma_f32_16x16x32_bf16(afr[m][1], bfr[n][1], acc[4 + m][n], 0, 0, 0);
      }
    __builtin_amdgcn_s_setprio(0);
    if (hn) asm volatile("s_waitcnt vmcnt(0)" ::: "memory");
    BARRIER();

    cur ^= 1;
  }

  // epilogue: col -> (mat, e) split; Q-prescale on cols < 2048
#pragma unroll
  for (int m = 0; m < 8; ++m)
#pragma unroll
    for (int n = 0; n < 6; ++n)
#pragma unroll
      for (int r = 0; r < 4; ++r) {
        const long row = abase + wr * 128 + m * 16 + orow + r;
        const int col = (int)bbase + wc * 96 + n * 16 + ocol;
        const float sc = ((col >> 11) == 0) ? qs : 1.0f;
        const long idx = (long)(col >> 11) * matStride + row * 2048 + (col & 2047);
        store_out(Cb, idx, acc[m][n][r] * sc);
      }
}

// ---- 128x256 2-phase bf16 GEMM (O-proj, proven R6 best-total) ------------

template <typename OUT_T>
__global__ __launch_bounds__(512, 2) void k_gemm2(const u16* __restrict__ A,
                                                  const u16* __restrict__ Bt,
                                                  OUT_T* __restrict__ Cb,
                                                  int M, int N, int K, long matStride,
                                                  float qs) {
  __shared__ u16 As[2][128][64];
  __shared__ u16 Bs[2][256][64];

  const int tid = threadIdx.x, wid = tid >> 6, lane = tid & 63;
  const int wr = wid >> 2, wc = wid & 3;
  const int frow = lane & 15, fk8 = (lane >> 4) * 8;
  const int orow = (lane >> 4) * 4, ocol = lane & 15;

  const int nwg = gridDim.x * gridDim.y;
  const int orig = blockIdx.y * gridDim.x + blockIdx.x;
  const int q = nwg >> 3, rr = nwg & 7;
  const int xcd = orig & 7, sl = orig >> 3;
  const int wg = (xcd < rr ? xcd * (q + 1) : rr * (q + 1) + (xcd - rr) * q) + sl;
  const int by = wg / gridDim.x, bx = wg % gridDim.x;

  const long abase = (long)by * 128, bbase = (long)bx * 256;

  const int bg0 = (wid >> 1) * 64 + (wid & 1) * 16;
  const int ag0 = ((wid & 1) << 6) + ((wid >> 1) << 3);

  f32x4_t acc[4][4];
#pragma unroll
  for (int m = 0; m < 4; ++m)
#pragma unroll
    for (int n = 0; n < 4; ++n)
#pragma unroll
      for (int r = 0; r < 4; ++r) acc[m][n][r] = 0.f;

  const int nt = K >> 6;

  stage16(Bt, bbase, K, 0, bg0, Bs[0], lane);
  stage16(Bt, bbase, K, 0, bg0 + 32, Bs[0], lane);
  stage8 (A,  abase, K, 0, ag0, As[0], lane);
  stage8 (A,  abase, K, 0, ag0 + 32, As[0], lane);
  asm volatile("s_waitcnt vmcnt(1)" ::: "memory");
  BARRIER();

  bf16x8_t bfr[4][2], afr[2][2];
  int cur = 0;

  for (int t = 0; t < nt; ++t) {
    const int ktn = (t + 1) << 6;
    const bool hn = (t + 1 < nt);
    const int nb = cur ^ 1;

#pragma unroll
    for (int n = 0; n < 4; ++n) {
      const int r = wc * 64 + n * 16 + frow;
      bfr[n][0] = *reinterpret_cast<const bf16x8_t*>(&Bs[cur][r][sw8(r, fk8)]);
      bfr[n][1] = *reinterpret_cast<const bf16x8_t*>(&Bs[cur][r][sw8(r, 32 + fk8)]);
    }
#pragma unroll
    for (int m = 0; m < 2; ++m) {
      const int r = wr * 64 + m * 16 + frow;
      afr[m][0] = *reinterpret_cast<const bf16x8_t*>(&As[cur][r][sw8(r, fk8)]);
      afr[m][1] = *reinterpret_cast<const bf16x8_t*>(&As[cur][r][sw8(r, 32 + fk8)]);
    }
    if (hn) {
      stage16(Bt, bbase, K, ktn, bg0, Bs[nb], lane);
      stage16(Bt, bbase, K, ktn, bg0 + 32, Bs[nb], lane);
    }
    BARRIER();
    WAITLGKM();
    __builtin_amdgcn_s_setprio(1);
#pragma unroll
    for (int m = 0; m < 2; ++m)
#pragma unroll
      for (int n = 0; n < 4; ++n) {
        acc[m][n] = __builtin_amdgcn_mfma_f32_16x16x32_bf16(afr[m][0], bfr[n][0], acc[m][n], 0, 0, 0);
        acc[m][n] = __builtin_amdgcn_mfma_f32_16x16x32_bf16(afr[m][1], bfr[n][1], acc[m][n], 0, 0, 0);
      }
    __builtin_amdgcn_s_setprio(0);
    if (hn) asm volatile("s_waitcnt vmcnt(4)" ::: "memory");
    else    asm volatile("s_waitcnt vmcnt(0)" ::: "memory");
    BARRIER();

#pragma unroll
    for (int m = 0; m < 2; ++m) {
      const int r = wr * 64 + 32 + m * 16 + frow;
      afr[m][0] = *reinterpret_cast<const bf16x8_t*>(&As[cur][r][sw8(r, fk8)]);
      afr[m][1] = *reinterpret_cast<const bf16x8_t*>(&As[cur][r][sw8(r, 32 + fk8)]);
    }
    if (hn) {
      stage8(A, abase, K, ktn, ag0, As[nb], lane);
      stage8(A, abase, K, ktn, ag0 + 32, As[nb], lane);
    }
    BARRIER();
    WAITLGKM();
    __builtin_amdgcn_s_setprio(1);
#pragma unroll
    for (int m = 0; m < 2; ++m)
#pragma unroll
      for (int n = 0; n < 4; ++n) {
        acc[2 + m][n] = __builtin_amdgcn_mfma_f32_16x16x32_bf16(afr[m][0], bfr[n][0], acc[2 + m][n], 0, 0, 0);
        acc[2 + m][n] = __builtin_amdgcn_mfma_f32_16x16x32_bf16(afr[m][1], bfr[n][1], acc[2 + m][n], 0, 0, 0);
      }
    __builtin_amdgcn_s_setprio(0);
    if (hn) asm volatile("s_waitcnt vmcnt(1)" ::: "memory");
    BARRIER();

    cur ^= 1;
  }

#pragma unroll
  for (int m = 0; m < 4; ++m)
#pragma unroll
    for (int n = 0; n < 4; ++n)
#pragma unroll
      for (int r = 0; r < 4; ++r) {
        const long row = abase + wr * 64 + m * 16 + orow + r;
        const int col = (int)bbase + wc * 64 + n * 16 + ocol;
        const float sc = ((col >> 11) == 0) ? qs : 1.0f;
        const long idx = (long)(col >> 11) * matStride + row * 2048 + (col & 2047);
        store_out(Cb, idx, acc[m][n][r] * sc);
      }
}

// ---- flash attention, QBLK=64, log2-domain softmax (proven R5) -----------

__global__ __launch_bounds__(256) void k_attn(const u16* __restrict__ Q,
                                              const u16* __restrict__ Kb,
                                              const u16* __restrict__ Vt,
                                              u16* __restrict__ Out,
                                              int B, int S, int H, int D,
                                              float log2e) {
  __shared__ u16 Ks[64][128];
  __shared__ u16 Vs[128][64];
  __shared__ u16 Ps[64][64];

  const int tid = threadIdx.x, wid = tid >> 6, lane = tid & 63;

  const int nq = gridDim.x, nbh = gridDim.y;
  const int lin = blockIdx.x + nq * blockIdx.y;
  const int qb0 = lin / nbh;
  const int bh  = lin % nbh;
  const int qb  = (qb0 < nq / 2) ? qb0 : (nq + nq / 2 - 1 - qb0);

  const int b = bh / H, h = bh % H;
  const int Dh = D / H;

  const float slope2 = alibi_slope(h, H) * log2e;
  const long qrow0 = (long)b * S + qb * 64 + wid * 16;

  const int frow = lane & 15;
  const int fk8  = (lane >> 4) * 8;
  const int orow = (lane >> 4) * 4;
  const int ocol = lane & 15;

  bf16x8_t aq[4];
#pragma unroll
  for (int kk = 0; kk < 4; ++kk)
    aq[kk] = *reinterpret_cast<const bf16x8_t*>(
        Q + (qrow0 + frow) * (long)D + h * Dh + kk * 32 + fk8);

  float cw[4];
#pragma unroll
  for (int n = 0; n < 4; ++n) cw[n] = slope2 * (float)(n * 16 + ocol);

  f32x4_t oacc[8];
#pragma unroll
  for (int no = 0; no < 8; ++no)
#pragma unroll
    for (int r = 0; r < 4; ++r) oacc[no][r] = 0.f;

  float Mrun[4], lrun[4];
#pragma unroll
  for (int r = 0; r < 4; ++r) { Mrun[r] = -3.0e38f; lrun[r] = 0.f; }

  const u16* kbase = Kb + (long)b * S * D + h * Dh;
  const u16* vbase = Vt + (long)bh * Dh * S;

  const int ntile = qb + 1;

  for (int kt = 0; kt < ntile; ++kt) {
    __syncthreads();
#pragma unroll
    for (int i = 0; i < 4; ++i) {
      const int lr = i * 16 + wid * 4;
      const int r  = lr + (lane >> 4);
      gload_lds16(kbase + ((long)kt * 64 + r) * (long)D + sw8(r, (lane & 15) * 8), &Ks[lr][0]);
    }
#pragma unroll
    for (int i = 0; i < 4; ++i) {
      const int lr = i * 32 + wid * 8;
      const int r  = lr + (lane >> 3);
      gload_lds16(vbase + (long)r * S + kt * 64 + sw8(r, (lane & 7) * 8), &Vs[lr][0]);
    }
    __syncthreads();

    f32x4_t sacc[4];
#pragma unroll
    for (int n = 0; n < 4; ++n)
#pragma unroll
      for (int r = 0; r < 4; ++r) sacc[n][r] = 0.f;

#pragma unroll
    for (int kk = 0; kk < 4; ++kk) {
      bf16x8_t bk[4];
#pragma unroll
      for (int n = 0; n < 4; ++n) {
        const int krow = n * 16 + frow;
        bk[n] = *reinterpret_cast<const bf16x8_t*>(&Ks[krow][sw8(krow, kk * 32 + fk8)]);
      }
#pragma unroll
      for (int n = 0; n < 4; ++n)
        sacc[n] = __builtin_amdgcn_mfma_f32_16x16x32_bf16(aq[kk], bk[n], sacc[n], 0, 0, 0);
    }

    const float tb = slope2 * (float)(kt << 6);
    float cbn[4];
#pragma unroll
    for (int n = 0; n < 4; ++n) cbn[n] = tb + cw[n];

    float tmax[4];
#pragma unroll
    for (int r = 0; r < 4; ++r) tmax[r] = -3.0e38f;

    if (kt == qb) {
#pragma unroll
      for (int n = 0; n < 4; ++n)
#pragma unroll
        for (int r = 0; r < 4; ++r) {
          float v = sacc[n][r] + cbn[n];
          v = (n * 16 + ocol <= wid * 16 + orow + r) ? v : -1.0e30f;
          sacc[n][r] = v;
          tmax[r] = fmaxf(tmax[r], v);
        }
    } else {
#pragma unroll
      for (int n = 0; n < 4; ++n)
#pragma unroll
        for (int r = 0; r < 4; ++r) {
          const float v = sacc[n][r] + cbn[n];
          sacc[n][r] = v;
          tmax[r] = fmaxf(tmax[r], v);
        }
    }
#pragma unroll
    for (int r = 0; r < 4; ++r) {
      float t = tmax[r];
      t = fmaxf(t, __shfl_xor(t, 1));
      t = fmaxf(t, __shfl_xor(t, 2));
      t = fmaxf(t, __shfl_xor(t, 4));
      t = fmaxf(t, __shfl_xor(t, 8));
      tmax[r] = t;
    }

#pragma unroll
    for (int r = 0; r < 4; ++r) {
      const float mnew = fmaxf(Mrun[r], tmax[r]);
      const float alpha = exp2f(Mrun[r] - mnew);
      Mrun[r] = mnew;
      lrun[r] *= alpha;
#pragma unroll
      for (int no = 0; no < 8; ++no) oacc[no][r] *= alpha;
    }

    float tsum[4];
#pragma unroll
    for (int r = 0; r < 4; ++r) tsum[r] = 0.f;
#pragma unroll
    for (int n = 0; n < 4; ++n)
#pragma unroll
      for (int r = 0; r < 4; ++r) {
        const float p = exp2f(sacc[n][r] - Mrun[r]);
        tsum[r] += p;
        const int prow = wid * 16 + orow + r;
        Ps[prow][sw8(prow, n * 16 + ocol)] = f2bf(p);
      }
#pragma unroll
    for (int r = 0; r < 4; ++r) {
      float t = tsum[r];
      t += __shfl_xor(t, 1);
      t += __shfl_xor(t, 2);
      t += __shfl_xor(t, 4);
      t += __shfl_xor(t, 8);
      lrun[r] += t;
    }

    __syncthreads();

#pragma unroll
    for (int kk = 0; kk < 2; ++kk) {
      const int prow = wid * 16 + frow;
      bf16x8_t pa = *reinterpret_cast<const bf16x8_t*>(&Ps[prow][sw8(prow, kk * 32 + fk8)]);
#pragma unroll
      for (int no = 0; no < 8; ++no) {
        const int vrow = no * 16 + frow;
        bf16x8_t bv = *reinterpret_cast<const bf16x8_t*>(&Vs[vrow][sw8(vrow, kk * 32 + fk8)]);
        oacc[no] = __builtin_amdgcn_mfma_f32_16x16x32_bf16(pa, bv, oacc[no], 0, 0, 0);
      }
    }
  }

#pragma unroll
  for (int r = 0; r < 4; ++r) {
    const float rl = 1.0f / lrun[r];
    const long trow = qrow0 + orow + r;
#pragma unroll
    for (int no = 0; no < 8; ++no)
      Out[trow * (long)D + h * Dh + no * 16 + ocol] = f2bf(oacc[no][r] * rl);
  }
}

// ---- launch --------------------------------------------------------------

extern "C" void kernel_launch(void* const* d_in, const int* in_sizes, int n_in,
                              void* d_out, int out_size, void* d_ws, size_t ws_size,
                              hipStream_t stream) {
  const float* hs   = (const float*)d_in[0];
  const float* qkvw = (const float*)d_in[1];
  const float* ow   = (const float*)d_in[2];

  const int D = 2048, B = 2, H = 16;
  const long TD = (long)in_sizes[0];   // T*D = 8388608
  const long DD = (long)in_sizes[2];   // D*D = 4194304
  const int T = (int)(TD / D);         // 4096
  const int S = T / B;                 // 2048
  const int Dh = D / H;                // 128
  const float log2e = 1.44269504f;
  const float qs = (1.0f / sqrtf((float)Dh)) * log2e;  // Q prescale

  u16* ws  = (u16*)d_ws;
  u16* hsb = ws;                  // TD    (later reused as attn)
  u16* wt  = ws + TD;             // 3*DD  (later reused as vt)
  u16* owt = wt + 3 * DD;         // DD
  u16* qkv = owt + DD;            // 3*TD  [Q | K | V]
  u16* vt   = wt;                 // TD    (overlay; wt dead after QKV GEMM)
  u16* attn = hsb;                // TD    (overlay; hsb dead after QKV GEMM)

  // 1) hidden -> bf16
  k_cast_bf16<<<dim3((unsigned)(TD / 1024)), 256, 0, stream>>>(hs, hsb, TD);
  // 2) qkv weights: cast + transpose to [3][E][D] (== fused Bt [6144][2048])
  k_transpose_cast<<<dim3(D / 32, D / 32, 3), 256, 0, stream>>>(qkvw, wt, D, D);
  // 3) o_proj weight: cast + transpose to [E][D]
  k_transpose_cast<<<dim3(D / 32, D / 32, 1), 256, 0, stream>>>(ow, owt, D, D);
  // 4) fused QKV projection: 256x384 tiles -> 16x16 = 256 blocks = 1 round
  k_gemm384<u16><<<dim3((3 * D) / 384, T / 256), 512, 0, stream>>>(
      hsb, wt, qkv, T, 3 * D, D, TD, qs);
  // 5) V -> Vt[bh][Dh][S]
  k_transpose_v<<<dim3(S / 32, Dh / 32, B * H), 256, 0, stream>>>(
      qkv + 2 * TD, vt, S, D, Dh, H);
  // 6) attention (QBLK=64, log2 domain)
  k_attn<<<dim3(S / 64, B * H), 256, 0, stream>>>(
      qkv, qkv + TD, vt, attn, B, S, H, D, log2e);
  // 7) output projection -> f32 d_out (128x256 tiles: 8x32 = 256 blocks = 1 round)
  k_gemm2<float><<<dim3(D / 256, T / 128), 512, 0, stream>>>(
      attn, owt, (float*)d_out, T, D, D, 0L, 1.0f);
}

// Round 12
// 312.583 us; speedup vs baseline: 1.4908x; 1.4908x over previous
//
#include <hip/hip_runtime.h>
#include <math.h>
#include <stdint.h>

typedef __bf16 bf16x8_t __attribute__((ext_vector_type(8)));
typedef float  f32x4_t  __attribute__((ext_vector_type(4)));
typedef unsigned short u16;

// ---- helpers -------------------------------------------------------------

__device__ __forceinline__ u16 f2bf(float f) {
  unsigned u = __float_as_uint(f);
  u += 0x7FFFu + ((u >> 16) & 1u);
  return (u16)(u >> 16);
}

__device__ __forceinline__ void gload_lds16(const u16* gsrc, u16* ldst) {
  // async global->LDS, 16B per lane; LDS dest = wave-uniform base + lane*16
  __builtin_amdgcn_global_load_lds(
      (__attribute__((address_space(1))) void*)(const_cast<u16*>(gsrc)),
      (__attribute__((address_space(3))) void*)(ldst),
      16, 0, 0);
}

// XOR swizzle for 128B rows (64 bf16): byte ^= ((row&7)<<4) == elem ^= ((row&7)<<3)
__device__ __forceinline__ int sw8(int row, int e) { return e ^ ((row & 7) << 3); }

__device__ __forceinline__ void store_out(float* C, long idx, float v) { C[idx] = v; }
__device__ __forceinline__ void store_out(u16* C, long idx, float v) { C[idx] = f2bf(v); }

__device__ __forceinline__ float alibi_slope(int h, int H) {
  int cp2 = 1, lg = 0;
  while (cp2 * 2 <= H) { cp2 *= 2; lg++; }
  if (h < cp2) {
    double e = exp2((double)-(lg - 3));
    return (float)exp2(-e * (double)(h + 1));
  } else {
    double e = exp2((double)-(lg + 1 - 3));
    return (float)exp2(-e * (double)(2 * (h - cp2) + 1));
  }
}

#define FENCE() asm volatile("" ::: "memory")
#define BARRIER() do { FENCE(); __builtin_amdgcn_s_barrier(); \
                       __builtin_amdgcn_sched_barrier(0); FENCE(); } while (0)
#define WAITLGKM() do { asm volatile("s_waitcnt lgkmcnt(0)" ::: "memory"); \
                        __builtin_amdgcn_sched_barrier(0); } while (0)

// ---- elementwise cast f32 -> bf16 ---------------------------------------

__global__ __launch_bounds__(256) void k_cast_bf16(const float* __restrict__ in,
                                                   u16* __restrict__ out, long n) {
  long i = ((long)blockIdx.x * 256 + threadIdx.x) * 4;
  if (i + 3 < n) {
    float4 v = *reinterpret_cast<const float4*>(in + i);
    ushort4 o;
    o.x = f2bf(v.x); o.y = f2bf(v.y); o.z = f2bf(v.z); o.w = f2bf(v.w);
    *reinterpret_cast<ushort4*>(out + i) = o;
  }
}

// ---- transpose + cast: out[z][c][r] = bf16(in[z][r][c]) ------------------

__global__ __launch_bounds__(256) void k_transpose_cast(const float* __restrict__ in,
                                                        u16* __restrict__ out,
                                                        int R, int C) {
  __shared__ float tile[32][33];
  const float* inz = in + (long)blockIdx.z * R * C;
  u16* outz = out + (long)blockIdx.z * R * C;
  const int tx = threadIdx.x & 31, ty = threadIdx.x >> 5;
  const int r0 = blockIdx.y * 32, c0 = blockIdx.x * 32;
#pragma unroll
  for (int i = 0; i < 4; ++i)
    tile[ty + i * 8][tx] = inz[(long)(r0 + ty + i * 8) * C + c0 + tx];
  __syncthreads();
#pragma unroll
  for (int i = 0; i < 4; ++i)
    outz[(long)(c0 + ty + i * 8) * R + r0 + tx] = f2bf(tile[tx][ty + i * 8]);
}

// ---- per-(b,h) transpose of V: [S,Dh slice of D] -> Vt[bh][Dh][S] --------

__global__ __launch_bounds__(256) void k_transpose_v(const u16* __restrict__ V,
                                                     u16* __restrict__ Vt,
                                                     int S, int D, int Dh, int H) {
  __shared__ u16 tile[32][33];
  const int bh = blockIdx.z, b = bh / H, h = bh % H;
  const int tx = threadIdx.x & 31, ty = threadIdx.x >> 5;
  const int s0 = blockIdx.x * 32, d0 = blockIdx.y * 32;
  const u16* vin = V + (long)b * S * D + (long)h * Dh;
#pragma unroll
  for (int i = 0; i < 4; ++i)
    tile[ty + i * 8][tx] = vin[(long)(s0 + ty + i * 8) * D + d0 + tx];
  __syncthreads();
  u16* vout = Vt + (long)bh * Dh * S;
#pragma unroll
  for (int i = 0; i < 4; ++i)
    vout[(long)(d0 + ty + i * 8) * S + s0 + tx] = tile[tx][ty + i * 8];
}

// ---- staging helpers (linear LDS dest + inverse-swizzled global source) --

__device__ __forceinline__ void stage16(const u16* __restrict__ g, long grow0, int K,
                                        int kt, int lr0, u16 (*lds)[64], int lane) {
  const int e = (lane & 7) * 8;
#pragma unroll
  for (int i = 0; i < 2; ++i) {
    const int r = lr0 + i * 8 + (lane >> 3);
    gload_lds16(g + (grow0 + r) * (long)K + kt + (e ^ ((r & 7) << 3)), &lds[lr0 + i * 8][0]);
  }
}

__device__ __forceinline__ void stage8(const u16* __restrict__ g, long grow0, int K,
                                       int kt, int lr0, u16 (*lds)[64], int lane) {
  const int e = (lane & 7) * 8;
  const int r = lr0 + (lane >> 3);
  gload_lds16(g + (grow0 + r) * (long)K + kt + (e ^ ((r & 7) << 3)), &lds[lr0][0]);
}

// ---- 128x256 2-phase bf16 GEMM (used for BOTH QKV and O-proj) ------------
// C[M,N] = A[M,K]*Bt[N,K]^T. 8 waves 2Mx4N, wave 64x64 (acc[4][4]).
// LDS 96KB double-buffered, swizzled. Measured block time ~25-38us at
// K=2048. QKV: grid 24x32 = 768 blocks = 3 full-machine rounds (beats
// k_gemm8's 1.5 rounds x 87us blocks = 131us). O-proj: 8x32 = 256 = 1 round.
// Epilogue: col -> (mat = col>>11, e = col&2047); qs prescale on cols<2048.

template <typename OUT_T>
__global__ __launch_bounds__(512, 2) void k_gemm2(const u16* __restrict__ A,
                                                  const u16* __restrict__ Bt,
                                                  OUT_T* __restrict__ Cb,
                                                  int M, int N, int K, long matStride,
                                                  float qs) {
  __shared__ u16 As[2][128][64];
  __shared__ u16 Bs[2][256][64];

  const int tid = threadIdx.x, wid = tid >> 6, lane = tid & 63;
  const int wr = wid >> 2, wc = wid & 3;
  const int frow = lane & 15, fk8 = (lane >> 4) * 8;
  const int orow = (lane >> 4) * 4, ocol = lane & 15;

  // T1: bijective XCD-aware swizzle
  const int nwg = gridDim.x * gridDim.y;
  const int orig = blockIdx.y * gridDim.x + blockIdx.x;
  const int q = nwg >> 3, rr = nwg & 7;
  const int xcd = orig & 7, sl = orig >> 3;
  const int wg = (xcd < rr ? xcd * (q + 1) : rr * (q + 1) + (xcd - rr) * q) + sl;
  const int by = wg / gridDim.x, bx = wg % gridDim.x;

  const long abase = (long)by * 128, bbase = (long)bx * 256;

  const int bg0 = (wid >> 1) * 64 + (wid & 1) * 16;
  const int ag0 = ((wid & 1) << 6) + ((wid >> 1) << 3);

  f32x4_t acc[4][4];
#pragma unroll
  for (int m = 0; m < 4; ++m)
#pragma unroll
    for (int n = 0; n < 4; ++n)
#pragma unroll
      for (int r = 0; r < 4; ++r) acc[m][n][r] = 0.f;

  const int nt = K >> 6;

  stage16(Bt, bbase, K, 0, bg0, Bs[0], lane);
  stage16(Bt, bbase, K, 0, bg0 + 32, Bs[0], lane);
  stage8 (A,  abase, K, 0, ag0, As[0], lane);
  stage8 (A,  abase, K, 0, ag0 + 32, As[0], lane);
  asm volatile("s_waitcnt vmcnt(1)" ::: "memory");
  BARRIER();

  bf16x8_t bfr[4][2], afr[2][2];
  int cur = 0;

  for (int t = 0; t < nt; ++t) {
    const int ktn = (t + 1) << 6;
    const bool hn = (t + 1 < nt);
    const int nb = cur ^ 1;

    // ---- phase 1: all B-frags + A m0-1; stage next-B
#pragma unroll
    for (int n = 0; n < 4; ++n) {
      const int r = wc * 64 + n * 16 + frow;
      bfr[n][0] = *reinterpret_cast<const bf16x8_t*>(&Bs[cur][r][sw8(r, fk8)]);
      bfr[n][1] = *reinterpret_cast<const bf16x8_t*>(&Bs[cur][r][sw8(r, 32 + fk8)]);
    }
#pragma unroll
    for (int m = 0; m < 2; ++m) {
      const int r = wr * 64 + m * 16 + frow;
      afr[m][0] = *reinterpret_cast<const bf16x8_t*>(&As[cur][r][sw8(r, fk8)]);
      afr[m][1] = *reinterpret_cast<const bf16x8_t*>(&As[cur][r][sw8(r, 32 + fk8)]);
    }
    if (hn) {
      stage16(Bt, bbase, K, ktn, bg0, Bs[nb], lane);
      stage16(Bt, bbase, K, ktn, bg0 + 32, Bs[nb], lane);
    }
    BARRIER();
    WAITLGKM();
    __builtin_amdgcn_s_setprio(1);
#pragma unroll
    for (int m = 0; m < 2; ++m)
#pragma unroll
      for (int n = 0; n < 4; ++n) {
        acc[m][n] = __builtin_amdgcn_mfma_f32_16x16x32_bf16(afr[m][0], bfr[n][0], acc[m][n], 0, 0, 0);
        acc[m][n] = __builtin_amdgcn_mfma_f32_16x16x32_bf16(afr[m][1], bfr[n][1], acc[m][n], 0, 0, 0);
      }
    __builtin_amdgcn_s_setprio(0);
    if (hn) asm volatile("s_waitcnt vmcnt(4)" ::: "memory");
    else    asm volatile("s_waitcnt vmcnt(0)" ::: "memory");
    BARRIER();

    // ---- phase 2: A m2-3; stage next-A
#pragma unroll
    for (int m = 0; m < 2; ++m) {
      const int r = wr * 64 + 32 + m * 16 + frow;
      afr[m][0] = *reinterpret_cast<const bf16x8_t*>(&As[cur][r][sw8(r, fk8)]);
      afr[m][1] = *reinterpret_cast<const bf16x8_t*>(&As[cur][r][sw8(r, 32 + fk8)]);
    }
    if (hn) {
      stage8(A, abase, K, ktn, ag0, As[nb], lane);
      stage8(A, abase, K, ktn, ag0 + 32, As[nb], lane);
    }
    BARRIER();
    WAITLGKM();
    __builtin_amdgcn_s_setprio(1);
#pragma unroll
    for (int m = 0; m < 2; ++m)
#pragma unroll
      for (int n = 0; n < 4; ++n) {
        acc[2 + m][n] = __builtin_amdgcn_mfma_f32_16x16x32_bf16(afr[m][0], bfr[n][0], acc[2 + m][n], 0, 0, 0);
        acc[2 + m][n] = __builtin_amdgcn_mfma_f32_16x16x32_bf16(afr[m][1], bfr[n][1], acc[2 + m][n], 0, 0, 0);
      }
    __builtin_amdgcn_s_setprio(0);
    if (hn) asm volatile("s_waitcnt vmcnt(1)" ::: "memory");
    BARRIER();

    cur ^= 1;
  }

#pragma unroll
  for (int m = 0; m < 4; ++m)
#pragma unroll
    for (int n = 0; n < 4; ++n)
#pragma unroll
      for (int r = 0; r < 4; ++r) {
        const long row = abase + wr * 64 + m * 16 + orow + r;
        const int col = (int)bbase + wc * 64 + n * 16 + ocol;
        const float sc = ((col >> 11) == 0) ? qs : 1.0f;
        const long idx = (long)(col >> 11) * matStride + row * 2048 + (col & 2047);
        store_out(Cb, idx, acc[m][n][r] * sc);
      }
}

// ---- flash attention, QBLK=64, log2-domain softmax (proven R5) -----------

__global__ __launch_bounds__(256) void k_attn(const u16* __restrict__ Q,
                                              const u16* __restrict__ Kb,
                                              const u16* __restrict__ Vt,
                                              u16* __restrict__ Out,
                                              int B, int S, int H, int D,
                                              float log2e) {
  __shared__ u16 Ks[64][128];
  __shared__ u16 Vs[128][64];
  __shared__ u16 Ps[64][64];

  const int tid = threadIdx.x, wid = tid >> 6, lane = tid & 63;

  const int nq = gridDim.x, nbh = gridDim.y;
  const int lin = blockIdx.x + nq * blockIdx.y;
  const int qb0 = lin / nbh;
  const int bh  = lin % nbh;
  const int qb  = (qb0 < nq / 2) ? qb0 : (nq + nq / 2 - 1 - qb0);

  const int b = bh / H, h = bh % H;
  const int Dh = D / H;

  const float slope2 = alibi_slope(h, H) * log2e;
  const long qrow0 = (long)b * S + qb * 64 + wid * 16;

  const int frow = lane & 15;
  const int fk8  = (lane >> 4) * 8;
  const int orow = (lane >> 4) * 4;
  const int ocol = lane & 15;

  bf16x8_t aq[4];
#pragma unroll
  for (int kk = 0; kk < 4; ++kk)
    aq[kk] = *reinterpret_cast<const bf16x8_t*>(
        Q + (qrow0 + frow) * (long)D + h * Dh + kk * 32 + fk8);

  float cw[4];
#pragma unroll
  for (int n = 0; n < 4; ++n) cw[n] = slope2 * (float)(n * 16 + ocol);

  f32x4_t oacc[8];
#pragma unroll
  for (int no = 0; no < 8; ++no)
#pragma unroll
    for (int r = 0; r < 4; ++r) oacc[no][r] = 0.f;

  float Mrun[4], lrun[4];
#pragma unroll
  for (int r = 0; r < 4; ++r) { Mrun[r] = -3.0e38f; lrun[r] = 0.f; }

  const u16* kbase = Kb + (long)b * S * D + h * Dh;
  const u16* vbase = Vt + (long)bh * Dh * S;

  const int ntile = qb + 1;

  for (int kt = 0; kt < ntile; ++kt) {
    __syncthreads();
#pragma unroll
    for (int i = 0; i < 4; ++i) {
      const int lr = i * 16 + wid * 4;
      const int r  = lr + (lane >> 4);
      gload_lds16(kbase + ((long)kt * 64 + r) * (long)D + sw8(r, (lane & 15) * 8), &Ks[lr][0]);
    }
#pragma unroll
    for (int i = 0; i < 4; ++i) {
      const int lr = i * 32 + wid * 8;
      const int r  = lr + (lane >> 3);
      gload_lds16(vbase + (long)r * S + kt * 64 + sw8(r, (lane & 7) * 8), &Vs[lr][0]);
    }
    __syncthreads();

    f32x4_t sacc[4];
#pragma unroll
    for (int n = 0; n < 4; ++n)
#pragma unroll
      for (int r = 0; r < 4; ++r) sacc[n][r] = 0.f;

#pragma unroll
    for (int kk = 0; kk < 4; ++kk) {
      bf16x8_t bk[4];
#pragma unroll
      for (int n = 0; n < 4; ++n) {
        const int krow = n * 16 + frow;
        bk[n] = *reinterpret_cast<const bf16x8_t*>(&Ks[krow][sw8(krow, kk * 32 + fk8)]);
      }
#pragma unroll
      for (int n = 0; n < 4; ++n)
        sacc[n] = __builtin_amdgcn_mfma_f32_16x16x32_bf16(aq[kk], bk[n], sacc[n], 0, 0, 0);
    }

    const float tb = slope2 * (float)(kt << 6);
    float cbn[4];
#pragma unroll
    for (int n = 0; n < 4; ++n) cbn[n] = tb + cw[n];

    float tmax[4];
#pragma unroll
    for (int r = 0; r < 4; ++r) tmax[r] = -3.0e38f;

    if (kt == qb) {
#pragma unroll
      for (int n = 0; n < 4; ++n)
#pragma unroll
        for (int r = 0; r < 4; ++r) {
          float v = sacc[n][r] + cbn[n];
          v = (n * 16 + ocol <= wid * 16 + orow + r) ? v : -1.0e30f;
          sacc[n][r] = v;
          tmax[r] = fmaxf(tmax[r], v);
        }
    } else {
#pragma unroll
      for (int n = 0; n < 4; ++n)
#pragma unroll
        for (int r = 0; r < 4; ++r) {
          const float v = sacc[n][r] + cbn[n];
          sacc[n][r] = v;
          tmax[r] = fmaxf(tmax[r], v);
        }
    }
#pragma unroll
    for (int r = 0; r < 4; ++r) {
      float t = tmax[r];
      t = fmaxf(t, __shfl_xor(t, 1));
      t = fmaxf(t, __shfl_xor(t, 2));
      t = fmaxf(t, __shfl_xor(t, 4));
      t = fmaxf(t, __shfl_xor(t, 8));
      tmax[r] = t;
    }

#pragma unroll
    for (int r = 0; r < 4; ++r) {
      const float mnew = fmaxf(Mrun[r], tmax[r]);
      const float alpha = exp2f(Mrun[r] - mnew);
      Mrun[r] = mnew;
      lrun[r] *= alpha;
#pragma unroll
      for (int no = 0; no < 8; ++no) oacc[no][r] *= alpha;
    }

    float tsum[4];
#pragma unroll
    for (int r = 0; r < 4; ++r) tsum[r] = 0.f;
#pragma unroll
    for (int n = 0; n < 4; ++n)
#pragma unroll
      for (int r = 0; r < 4; ++r) {
        const float p = exp2f(sacc[n][r] - Mrun[r]);
        tsum[r] += p;
        const int prow = wid * 16 + orow + r;
        Ps[prow][sw8(prow, n * 16 + ocol)] = f2bf(p);
      }
#pragma unroll
    for (int r = 0; r < 4; ++r) {
      float t = tsum[r];
      t += __shfl_xor(t, 1);
      t += __shfl_xor(t, 2);
      t += __shfl_xor(t, 4);
      t += __shfl_xor(t, 8);
      lrun[r] += t;
    }

    __syncthreads();

#pragma unroll
    for (int kk = 0; kk < 2; ++kk) {
      const int prow = wid * 16 + frow;
      bf16x8_t pa = *reinterpret_cast<const bf16x8_t*>(&Ps[prow][sw8(prow, kk * 32 + fk8)]);
#pragma unroll
      for (int no = 0; no < 8; ++no) {
        const int vrow = no * 16 + frow;
        bf16x8_t bv = *reinterpret_cast<const bf16x8_t*>(&Vs[vrow][sw8(vrow, kk * 32 + fk8)]);
        oacc[no] = __builtin_amdgcn_mfma_f32_16x16x32_bf16(pa, bv, oacc[no], 0, 0, 0);
      }
    }
  }

#pragma unroll
  for (int r = 0; r < 4; ++r) {
    const float rl = 1.0f / lrun[r];
    const long trow = qrow0 + orow + r;
#pragma unroll
    for (int no = 0; no < 8; ++no)
      Out[trow * (long)D + h * Dh + no * 16 + ocol] = f2bf(oacc[no][r] * rl);
  }
}

// ---- launch --------------------------------------------------------------

extern "C" void kernel_launch(void* const* d_in, const int* in_sizes, int n_in,
                              void* d_out, int out_size, void* d_ws, size_t ws_size,
                              hipStream_t stream) {
  const float* hs   = (const float*)d_in[0];
  const float* qkvw = (const float*)d_in[1];
  const float* ow   = (const float*)d_in[2];

  const int D = 2048, B = 2, H = 16;
  const long TD = (long)in_sizes[0];   // T*D = 8388608
  const long DD = (long)in_sizes[2];   // D*D = 4194304
  const int T = (int)(TD / D);         // 4096
  const int S = T / B;                 // 2048
  const int Dh = D / H;                // 128
  const float log2e = 1.44269504f;
  const float qs = (1.0f / sqrtf((float)Dh)) * log2e;  // Q prescale

  u16* ws  = (u16*)d_ws;
  u16* hsb = ws;                  // TD    (later reused as attn)
  u16* wt  = ws + TD;             // 3*DD  (later reused as vt)
  u16* owt = wt + 3 * DD;         // DD
  u16* qkv = owt + DD;            // 3*TD  [Q | K | V]
  u16* vt   = wt;                 // TD    (overlay; wt dead after QKV GEMM)
  u16* attn = hsb;                // TD    (overlay; hsb dead after QKV GEMM)

  // 1) hidden -> bf16
  k_cast_bf16<<<dim3((unsigned)(TD / 1024)), 256, 0, stream>>>(hs, hsb, TD);
  // 2) qkv weights: cast + transpose to [3][E][D] (== fused Bt [6144][2048])
  k_transpose_cast<<<dim3(D / 32, D / 32, 3), 256, 0, stream>>>(qkvw, wt, D, D);
  // 3) o_proj weight: cast + transpose to [E][D]
  k_transpose_cast<<<dim3(D / 32, D / 32, 1), 256, 0, stream>>>(ow, owt, D, D);
  // 4) fused QKV projection on k_gemm2: 24x32 = 768 blocks = 3 full rounds
  k_gemm2<u16><<<dim3((3 * D) / 256, T / 128), 512, 0, stream>>>(
      hsb, wt, qkv, T, 3 * D, D, TD, qs);
  // 5) V -> Vt[bh][Dh][S]
  k_transpose_v<<<dim3(S / 32, Dh / 32, B * H), 256, 0, stream>>>(
      qkv + 2 * TD, vt, S, D, Dh, H);
  // 6) attention (QBLK=64, log2 domain)
  k_attn<<<dim3(S / 64, B * H), 256, 0, stream>>>(
      qkv, qkv + TD, vt, attn, B, S, H, D, log2e);
  // 7) output projection -> f32 d_out (128x256 tiles: 8x32 = 256 blocks = 1 round)
  k_gemm2<float><<<dim3(D / 256, T / 128), 512, 0, stream>>>(
      attn, owt, (float*)d_out, T, D, D, 0L, 1.0f);
}

// Round 13
// 293.673 us; speedup vs baseline: 1.5868x; 1.0644x over previous
//
#include <hip/hip_runtime.h>
#include <math.h>
#include <stdint.h>

typedef __bf16 bf16x8_t __attribute__((ext_vector_type(8)));
typedef float  f32x4_t  __attribute__((ext_vector_type(4)));
typedef unsigned short u16;

// ---- helpers -------------------------------------------------------------

__device__ __forceinline__ u16 f2bf(float f) {
  unsigned u = __float_as_uint(f);
  u += 0x7FFFu + ((u >> 16) & 1u);
  return (u16)(u >> 16);
}

__device__ __forceinline__ void gload_lds16(const u16* gsrc, u16* ldst) {
  // async global->LDS, 16B per lane; LDS dest = wave-uniform base + lane*16
  __builtin_amdgcn_global_load_lds(
      (__attribute__((address_space(1))) void*)(const_cast<u16*>(gsrc)),
      (__attribute__((address_space(3))) void*)(ldst),
      16, 0, 0);
}

// XOR swizzle for 128B rows (64 bf16): byte ^= ((row&7)<<4) == elem ^= ((row&7)<<3)
__device__ __forceinline__ int sw8(int row, int e) { return e ^ ((row & 7) << 3); }

__device__ __forceinline__ void store_out(float* C, long idx, float v) { C[idx] = v; }
__device__ __forceinline__ void store_out(u16* C, long idx, float v) { C[idx] = f2bf(v); }

__device__ __forceinline__ float alibi_slope(int h, int H) {
  int cp2 = 1, lg = 0;
  while (cp2 * 2 <= H) { cp2 *= 2; lg++; }
  if (h < cp2) {
    double e = exp2((double)-(lg - 3));
    return (float)exp2(-e * (double)(h + 1));
  } else {
    double e = exp2((double)-(lg + 1 - 3));
    return (float)exp2(-e * (double)(2 * (h - cp2) + 1));
  }
}

#define FENCE() asm volatile("" ::: "memory")
#define BARRIER() do { FENCE(); __builtin_amdgcn_s_barrier(); \
                       __builtin_amdgcn_sched_barrier(0); FENCE(); } while (0)
#define WAITLGKM() do { asm volatile("s_waitcnt lgkmcnt(0)" ::: "memory"); \
                        __builtin_amdgcn_sched_barrier(0); } while (0)

// ---- elementwise cast f32 -> bf16 ---------------------------------------

__global__ __launch_bounds__(256) void k_cast_bf16(const float* __restrict__ in,
                                                   u16* __restrict__ out, long n) {
  long i = ((long)blockIdx.x * 256 + threadIdx.x) * 4;
  if (i + 3 < n) {
    float4 v = *reinterpret_cast<const float4*>(in + i);
    ushort4 o;
    o.x = f2bf(v.x); o.y = f2bf(v.y); o.z = f2bf(v.z); o.w = f2bf(v.w);
    *reinterpret_cast<ushort4*>(out + i) = o;
  }
}

// ---- transpose + cast: out[z][c][r] = bf16(in[z][r][c]) ------------------

__global__ __launch_bounds__(256) void k_transpose_cast(const float* __restrict__ in,
                                                        u16* __restrict__ out,
                                                        int R, int C) {
  __shared__ float tile[32][33];
  const float* inz = in + (long)blockIdx.z * R * C;
  u16* outz = out + (long)blockIdx.z * R * C;
  const int tx = threadIdx.x & 31, ty = threadIdx.x >> 5;
  const int r0 = blockIdx.y * 32, c0 = blockIdx.x * 32;
#pragma unroll
  for (int i = 0; i < 4; ++i)
    tile[ty + i * 8][tx] = inz[(long)(r0 + ty + i * 8) * C + c0 + tx];
  __syncthreads();
#pragma unroll
  for (int i = 0; i < 4; ++i)
    outz[(long)(c0 + ty + i * 8) * R + r0 + tx] = f2bf(tile[tx][ty + i * 8]);
}

// ---- per-(b,h) transpose of V: [S,Dh slice of D] -> Vt[bh][Dh][S] --------

__global__ __launch_bounds__(256) void k_transpose_v(const u16* __restrict__ V,
                                                     u16* __restrict__ Vt,
                                                     int S, int D, int Dh, int H) {
  __shared__ u16 tile[32][33];
  const int bh = blockIdx.z, b = bh / H, h = bh % H;
  const int tx = threadIdx.x & 31, ty = threadIdx.x >> 5;
  const int s0 = blockIdx.x * 32, d0 = blockIdx.y * 32;
  const u16* vin = V + (long)b * S * D + (long)h * Dh;
#pragma unroll
  for (int i = 0; i < 4; ++i)
    tile[ty + i * 8][tx] = vin[(long)(s0 + ty + i * 8) * D + d0 + tx];
  __syncthreads();
  u16* vout = Vt + (long)bh * Dh * S;
#pragma unroll
  for (int i = 0; i < 4; ++i)
    vout[(long)(d0 + ty + i * 8) * S + s0 + tx] = tile[tx][ty + i * 8];
}

// ---- staging helpers (linear LDS dest + inverse-swizzled global source) --

__device__ __forceinline__ void stage16(const u16* __restrict__ g, long grow0, int K,
                                        int kt, int lr0, u16 (*lds)[64], int lane) {
  const int e = (lane & 7) * 8;
#pragma unroll
  for (int i = 0; i < 2; ++i) {
    const int r = lr0 + i * 8 + (lane >> 3);
    gload_lds16(g + (grow0 + r) * (long)K + kt + (e ^ ((r & 7) << 3)), &lds[lr0 + i * 8][0]);
  }
}

__device__ __forceinline__ void stage8(const u16* __restrict__ g, long grow0, int K,
                                       int kt, int lr0, u16 (*lds)[64], int lane) {
  const int e = (lane & 7) * 8;
  const int r = lr0 + (lane >> 3);
  gload_lds16(g + (grow0 + r) * (long)K + kt + (e ^ ((r & 7) << 3)), &lds[lr0][0]);
}

// ---- 256x256 4-phase bf16 GEMM (QKV; best measured: 128.5us R10) ---------
// C[M,N] = A[M,K]*Bt[N,K]^T. Stage order A-h0@ph1, B-h0@ph2, B-h1@ph3,
// A-h1@ph4; counted vmcnt(4) at ph1/ph4 ends. qs prescales cols < 2048.

template <typename OUT_T>
__global__ __launch_bounds__(512, 2) void k_gemm8(const u16* __restrict__ A,
                                                  const u16* __restrict__ Bt,
                                                  OUT_T* __restrict__ Cb,
                                                  int M, int N, int K, long matStride,
                                                  float qs) {
  __shared__ u16 As[2][256][64];
  __shared__ u16 Bs[2][256][64];

  const int tid = threadIdx.x, wid = tid >> 6, lane = tid & 63;
  const int wr = wid >> 2, wc = wid & 3;
  const int frow = lane & 15, fk8 = (lane >> 4) * 8;
  const int orow = (lane >> 4) * 4, ocol = lane & 15;

  // T1: bijective XCD-aware swizzle
  const int nwg = gridDim.x * gridDim.y;
  const int orig = blockIdx.y * gridDim.x + blockIdx.x;
  const int q = nwg >> 3, rr = nwg & 7;
  const int xcd = orig & 7, sl = orig >> 3;
  const int wg = (xcd < rr ? xcd * (q + 1) : rr * (q + 1) + (xcd - rr) * q) + sl;
  const int by = wg / gridDim.x, bx = wg % gridDim.x;

  const long abase = (long)by * 256, bbase = (long)bx * 256;

  const int bg0 = (wid >> 1) * 64 + (wid & 1) * 16;
  const int ag0 = (wid >> 2) * 128 + (wid & 3) * 16;

  f32x4_t acc[8][4];
#pragma unroll
  for (int m = 0; m < 8; ++m)
#pragma unroll
    for (int n = 0; n < 4; ++n)
#pragma unroll
      for (int r = 0; r < 4; ++r) acc[m][n][r] = 0.f;

  const int nt = K >> 6;

  stage16(A, abase, K, 0, ag0, As[0], lane);
  stage16(Bt, bbase, K, 0, bg0, Bs[0], lane);
  stage16(Bt, bbase, K, 0, bg0 + 32, Bs[0], lane);
  stage16(A, abase, K, 0, ag0 + 64, As[0], lane);
  asm volatile("s_waitcnt vmcnt(4)" ::: "memory");
  BARRIER();

  bf16x8_t afr[4][2], bfr[4][2];
  int cur = 0;

  for (int t = 0; t < nt; ++t) {
    const int ktn = (t + 1) << 6;
    const bool hn = (t + 1 < nt);
    const int nb = cur ^ 1;

    // ---- phase 1: quadrant (mh0,nh0); stage A-h0(t+1)
#pragma unroll
    for (int m = 0; m < 4; ++m) {
      const int r = wr * 128 + m * 16 + frow;
      afr[m][0] = *reinterpret_cast<const bf16x8_t*>(&As[cur][r][sw8(r, fk8)]);
      afr[m][1] = *reinterpret_cast<const bf16x8_t*>(&As[cur][r][sw8(r, 32 + fk8)]);
    }
#pragma unroll
    for (int n = 0; n < 2; ++n) {
      const int r = wc * 64 + n * 16 + frow;
      bfr[n][0] = *reinterpret_cast<const bf16x8_t*>(&Bs[cur][r][sw8(r, fk8)]);
      bfr[n][1] = *reinterpret_cast<const bf16x8_t*>(&Bs[cur][r][sw8(r, 32 + fk8)]);
    }
    if (hn) stage16(A, abase, K, ktn, ag0, As[nb], lane);
    BARRIER();
    WAITLGKM();
    __builtin_amdgcn_s_setprio(1);
#pragma unroll
    for (int m = 0; m < 4; ++m)
#pragma unroll
      for (int n = 0; n < 2; ++n) {
        acc[m][n] = __builtin_amdgcn_mfma_f32_16x16x32_bf16(afr[m][0], bfr[n][0], acc[m][n], 0, 0, 0);
        acc[m][n] = __builtin_amdgcn_mfma_f32_16x16x32_bf16(afr[m][1], bfr[n][1], acc[m][n], 0, 0, 0);
      }
    __builtin_amdgcn_s_setprio(0);
    if (hn) asm volatile("s_waitcnt vmcnt(4)" ::: "memory");
    else    asm volatile("s_waitcnt vmcnt(2)" ::: "memory");
    BARRIER();

    // ---- phase 2: quadrant (mh0,nh1); stage B-h0(t+1)
#pragma unroll
    for (int n = 0; n < 2; ++n) {
      const int r = wc * 64 + 32 + n * 16 + frow;
      bfr[2 + n][0] = *reinterpret_cast<const bf16x8_t*>(&Bs[cur][r][sw8(r, fk8)]);
      bfr[2 + n][1] = *reinterpret_cast<const bf16x8_t*>(&Bs[cur][r][sw8(r, 32 + fk8)]);
    }
    if (hn) stage16(Bt, bbase, K, ktn, bg0, Bs[nb], lane);
    BARRIER();
    WAITLGKM();
    __builtin_amdgcn_s_setprio(1);
#pragma unroll
    for (int m = 0; m < 4; ++m)
#pragma unroll
      for (int n = 0; n < 2; ++n) {
        acc[m][2 + n] = __builtin_amdgcn_mfma_f32_16x16x32_bf16(afr[m][0], bfr[2 + n][0], acc[m][2 + n], 0, 0, 0);
        acc[m][2 + n] = __builtin_amdgcn_mfma_f32_16x16x32_bf16(afr[m][1], bfr[2 + n][1], acc[m][2 + n], 0, 0, 0);
      }
    __builtin_amdgcn_s_setprio(0);
    if (!hn) asm volatile("s_waitcnt vmcnt(0)" ::: "memory");
    BARRIER();

    // ---- phase 3: quadrant (mh1,nh0); stage B-h1(t+1)
#pragma unroll
    for (int m = 0; m < 4; ++m) {
      const int r = wr * 128 + 64 + m * 16 + frow;
      afr[m][0] = *reinterpret_cast<const bf16x8_t*>(&As[cur][r][sw8(r, fk8)]);
      afr[m][1] = *reinterpret_cast<const bf16x8_t*>(&As[cur][r][sw8(r, 32 + fk8)]);
    }
    if (hn) stage16(Bt, bbase, K, ktn, bg0 + 32, Bs[nb], lane);
    BARRIER();
    WAITLGKM();
    __builtin_amdgcn_s_setprio(1);
#pragma unroll
    for (int m = 0; m < 4; ++m)
#pragma unroll
      for (int n = 0; n < 2; ++n) {
        acc[4 + m][n] = __builtin_amdgcn_mfma_f32_16x16x32_bf16(afr[m][0], bfr[n][0], acc[4 + m][n], 0, 0, 0);
        acc[4 + m][n] = __builtin_amdgcn_mfma_f32_16x16x32_bf16(afr[m][1], bfr[n][1], acc[4 + m][n], 0, 0, 0);
      }
    __builtin_amdgcn_s_setprio(0);
    BARRIER();

    // ---- phase 4: quadrant (mh1,nh1); stage A-h1(t+1)
    if (hn) stage16(A, abase, K, ktn, ag0 + 64, As[nb], lane);
    __builtin_amdgcn_s_setprio(1);
#pragma unroll
    for (int m = 0; m < 4; ++m)
#pragma unroll
      for (int n = 0; n < 2; ++n) {
        acc[4 + m][2 + n] = __builtin_amdgcn_mfma_f32_16x16x32_bf16(afr[m][0], bfr[2 + n][0], acc[4 + m][2 + n], 0, 0, 0);
        acc[4 + m][2 + n] = __builtin_amdgcn_mfma_f32_16x16x32_bf16(afr[m][1], bfr[2 + n][1], acc[4 + m][2 + n], 0, 0, 0);
      }
    __builtin_amdgcn_s_setprio(0);
    if (hn) asm volatile("s_waitcnt vmcnt(4)" ::: "memory");
    BARRIER();

    cur ^= 1;
  }

#pragma unroll
  for (int m = 0; m < 8; ++m)
#pragma unroll
    for (int n = 0; n < 4; ++n)
#pragma unroll
      for (int r = 0; r < 4; ++r) {
        const long row = abase + wr * 128 + m * 16 + orow + r;
        const int col = (int)bbase + wc * 64 + n * 16 + ocol;
        const float sc = ((col >> 11) == 0) ? qs : 1.0f;
        const long idx = (long)(col >> 11) * matStride + row * 2048 + (col & 2047);
        store_out(Cb, idx, acc[m][n][r] * sc);
      }
}

// ---- 128x256 2-phase bf16 GEMM (O-proj: 8x32 = 256 blocks = 1 round) -----

template <typename OUT_T>
__global__ __launch_bounds__(512, 2) void k_gemm2(const u16* __restrict__ A,
                                                  const u16* __restrict__ Bt,
                                                  OUT_T* __restrict__ Cb,
                                                  int M, int N, int K, long matStride,
                                                  float qs) {
  __shared__ u16 As[2][128][64];
  __shared__ u16 Bs[2][256][64];

  const int tid = threadIdx.x, wid = tid >> 6, lane = tid & 63;
  const int wr = wid >> 2, wc = wid & 3;
  const int frow = lane & 15, fk8 = (lane >> 4) * 8;
  const int orow = (lane >> 4) * 4, ocol = lane & 15;

  const int nwg = gridDim.x * gridDim.y;
  const int orig = blockIdx.y * gridDim.x + blockIdx.x;
  const int q = nwg >> 3, rr = nwg & 7;
  const int xcd = orig & 7, sl = orig >> 3;
  const int wg = (xcd < rr ? xcd * (q + 1) : rr * (q + 1) + (xcd - rr) * q) + sl;
  const int by = wg / gridDim.x, bx = wg % gridDim.x;

  const long abase = (long)by * 128, bbase = (long)bx * 256;

  const int bg0 = (wid >> 1) * 64 + (wid & 1) * 16;
  const int ag0 = ((wid & 1) << 6) + ((wid >> 1) << 3);

  f32x4_t acc[4][4];
#pragma unroll
  for (int m = 0; m < 4; ++m)
#pragma unroll
    for (int n = 0; n < 4; ++n)
#pragma unroll
      for (int r = 0; r < 4; ++r) acc[m][n][r] = 0.f;

  const int nt = K >> 6;

  stage16(Bt, bbase, K, 0, bg0, Bs[0], lane);
  stage16(Bt, bbase, K, 0, bg0 + 32, Bs[0], lane);
  stage8 (A,  abase, K, 0, ag0, As[0], lane);
  stage8 (A,  abase, K, 0, ag0 + 32, As[0], lane);
  asm volatile("s_waitcnt vmcnt(1)" ::: "memory");
  BARRIER();

  bf16x8_t bfr[4][2], afr[2][2];
  int cur = 0;

  for (int t = 0; t < nt; ++t) {
    const int ktn = (t + 1) << 6;
    const bool hn = (t + 1 < nt);
    const int nb = cur ^ 1;

#pragma unroll
    for (int n = 0; n < 4; ++n) {
      const int r = wc * 64 + n * 16 + frow;
      bfr[n][0] = *reinterpret_cast<const bf16x8_t*>(&Bs[cur][r][sw8(r, fk8)]);
      bfr[n][1] = *reinterpret_cast<const bf16x8_t*>(&Bs[cur][r][sw8(r, 32 + fk8)]);
    }
#pragma unroll
    for (int m = 0; m < 2; ++m) {
      const int r = wr * 64 + m * 16 + frow;
      afr[m][0] = *reinterpret_cast<const bf16x8_t*>(&As[cur][r][sw8(r, fk8)]);
      afr[m][1] = *reinterpret_cast<const bf16x8_t*>(&As[cur][r][sw8(r, 32 + fk8)]);
    }
    if (hn) {
      stage16(Bt, bbase, K, ktn, bg0, Bs[nb], lane);
      stage16(Bt, bbase, K, ktn, bg0 + 32, Bs[nb], lane);
    }
    BARRIER();
    WAITLGKM();
    __builtin_amdgcn_s_setprio(1);
#pragma unroll
    for (int m = 0; m < 2; ++m)
#pragma unroll
      for (int n = 0; n < 4; ++n) {
        acc[m][n] = __builtin_amdgcn_mfma_f32_16x16x32_bf16(afr[m][0], bfr[n][0], acc[m][n], 0, 0, 0);
        acc[m][n] = __builtin_amdgcn_mfma_f32_16x16x32_bf16(afr[m][1], bfr[n][1], acc[m][n], 0, 0, 0);
      }
    __builtin_amdgcn_s_setprio(0);
    if (hn) asm volatile("s_waitcnt vmcnt(4)" ::: "memory");
    else    asm volatile("s_waitcnt vmcnt(0)" ::: "memory");
    BARRIER();

#pragma unroll
    for (int m = 0; m < 2; ++m) {
      const int r = wr * 64 + 32 + m * 16 + frow;
      afr[m][0] = *reinterpret_cast<const bf16x8_t*>(&As[cur][r][sw8(r, fk8)]);
      afr[m][1] = *reinterpret_cast<const bf16x8_t*>(&As[cur][r][sw8(r, 32 + fk8)]);
    }
    if (hn) {
      stage8(A, abase, K, ktn, ag0, As[nb], lane);
      stage8(A, abase, K, ktn, ag0 + 32, As[nb], lane);
    }
    BARRIER();
    WAITLGKM();
    __builtin_amdgcn_s_setprio(1);
#pragma unroll
    for (int m = 0; m < 2; ++m)
#pragma unroll
      for (int n = 0; n < 4; ++n) {
        acc[2 + m][n] = __builtin_amdgcn_mfma_f32_16x16x32_bf16(afr[m][0], bfr[n][0], acc[2 + m][n], 0, 0, 0);
        acc[2 + m][n] = __builtin_amdgcn_mfma_f32_16x16x32_bf16(afr[m][1], bfr[n][1], acc[2 + m][n], 0, 0, 0);
      }
    __builtin_amdgcn_s_setprio(0);
    if (hn) asm volatile("s_waitcnt vmcnt(1)" ::: "memory");
    BARRIER();

    cur ^= 1;
  }

#pragma unroll
  for (int m = 0; m < 4; ++m)
#pragma unroll
    for (int n = 0; n < 4; ++n)
#pragma unroll
      for (int r = 0; r < 4; ++r) {
        const long row = abase + wr * 64 + m * 16 + orow + r;
        const int col = (int)bbase + wc * 64 + n * 16 + ocol;
        const float sc = ((col >> 11) == 0) ? qs : 1.0f;
        const long idx = (long)(col >> 11) * matStride + row * 2048 + (col & 2047);
        store_out(Cb, idx, acc[m][n][r] * sc);
      }
}

// ---- flash attention, QBLK=64, log2-domain softmax -----------------------
// R13: DESCENDING k-tile order (ALiBi column bias slope2*k is largest at
// the diagonal -> running max set on tile 1, later tiles rarely exceed) +
// defer-max (T13, THR=11, wave-uniform __any; safe now that the P->PV
// barrier is in place) + setprio around MFMA clusters (m191: +4-7% attn).

__global__ __launch_bounds__(256) void k_attn(const u16* __restrict__ Q,
                                              const u16* __restrict__ Kb,
                                              const u16* __restrict__ Vt,
                                              u16* __restrict__ Out,
                                              int B, int S, int H, int D,
                                              float log2e) {
  __shared__ u16 Ks[64][128];
  __shared__ u16 Vs[128][64];
  __shared__ u16 Ps[64][64];

  const int tid = threadIdx.x, wid = tid >> 6, lane = tid & 63;

  const int nq = gridDim.x, nbh = gridDim.y;
  const int lin = blockIdx.x + nq * blockIdx.y;
  const int qb0 = lin / nbh;
  const int bh  = lin % nbh;
  const int qb  = (qb0 < nq / 2) ? qb0 : (nq + nq / 2 - 1 - qb0);

  const int b = bh / H, h = bh % H;
  const int Dh = D / H;

  const float slope2 = alibi_slope(h, H) * log2e;
  const long qrow0 = (long)b * S + qb * 64 + wid * 16;

  const int frow = lane & 15;
  const int fk8  = (lane >> 4) * 8;
  const int orow = (lane >> 4) * 4;
  const int ocol = lane & 15;

  bf16x8_t aq[4];
#pragma unroll
  for (int kk = 0; kk < 4; ++kk)
    aq[kk] = *reinterpret_cast<const bf16x8_t*>(
        Q + (qrow0 + frow) * (long)D + h * Dh + kk * 32 + fk8);

  float cw[4];
#pragma unroll
  for (int n = 0; n < 4; ++n) cw[n] = slope2 * (float)(n * 16 + ocol);

  f32x4_t oacc[8];
#pragma unroll
  for (int no = 0; no < 8; ++no)
#pragma unroll
    for (int r = 0; r < 4; ++r) oacc[no][r] = 0.f;

  float Mrun[4], lrun[4];
#pragma unroll
  for (int r = 0; r < 4; ++r) { Mrun[r] = -3.0e38f; lrun[r] = 0.f; }

  const u16* kbase = Kb + (long)b * S * D + h * Dh;
  const u16* vbase = Vt + (long)bh * Dh * S;

  // descending k-tiles: diagonal (masked, largest ALiBi bias) first
  for (int kt = qb; kt >= 0; --kt) {
    __syncthreads();
#pragma unroll
    for (int i = 0; i < 4; ++i) {
      const int lr = i * 16 + wid * 4;
      const int r  = lr + (lane >> 4);
      gload_lds16(kbase + ((long)kt * 64 + r) * (long)D + sw8(r, (lane & 15) * 8), &Ks[lr][0]);
    }
#pragma unroll
    for (int i = 0; i < 4; ++i) {
      const int lr = i * 32 + wid * 8;
      const int r  = lr + (lane >> 3);
      gload_lds16(vbase + (long)r * S + kt * 64 + sw8(r, (lane & 7) * 8), &Vs[lr][0]);
    }
    __syncthreads();

    f32x4_t sacc[4];
#pragma unroll
    for (int n = 0; n < 4; ++n)
#pragma unroll
      for (int r = 0; r < 4; ++r) sacc[n][r] = 0.f;

    __builtin_amdgcn_s_setprio(1);
#pragma unroll
    for (int kk = 0; kk < 4; ++kk) {
      bf16x8_t bk[4];
#pragma unroll
      for (int n = 0; n < 4; ++n) {
        const int krow = n * 16 + frow;
        bk[n] = *reinterpret_cast<const bf16x8_t*>(&Ks[krow][sw8(krow, kk * 32 + fk8)]);
      }
#pragma unroll
      for (int n = 0; n < 4; ++n)
        sacc[n] = __builtin_amdgcn_mfma_f32_16x16x32_bf16(aq[kk], bk[n], sacc[n], 0, 0, 0);
    }
    __builtin_amdgcn_s_setprio(0);

    const float tb = slope2 * (float)(kt << 6);
    float cbn[4];
#pragma unroll
    for (int n = 0; n < 4; ++n) cbn[n] = tb + cw[n];

    float tmax[4];
#pragma unroll
    for (int r = 0; r < 4; ++r) tmax[r] = -3.0e38f;

    if (kt == qb) {
#pragma unroll
      for (int n = 0; n < 4; ++n)
#pragma unroll
        for (int r = 0; r < 4; ++r) {
          float v = sacc[n][r] + cbn[n];
          v = (n * 16 + ocol <= wid * 16 + orow + r) ? v : -1.0e30f;
          sacc[n][r] = v;
          tmax[r] = fmaxf(tmax[r], v);
        }
    } else {
#pragma unroll
      for (int n = 0; n < 4; ++n)
#pragma unroll
        for (int r = 0; r < 4; ++r) {
          const float v = sacc[n][r] + cbn[n];
          sacc[n][r] = v;
          tmax[r] = fmaxf(tmax[r], v);
        }
    }
#pragma unroll
    for (int r = 0; r < 4; ++r) {
      float t = tmax[r];
      t = fmaxf(t, __shfl_xor(t, 1));
      t = fmaxf(t, __shfl_xor(t, 2));
      t = fmaxf(t, __shfl_xor(t, 4));
      t = fmaxf(t, __shfl_xor(t, 8));
      tmax[r] = t;
    }

    // defer-max (T13): skip O-rescale unless some row max grew past THR=11
    int need = 0;
#pragma unroll
    for (int r = 0; r < 4; ++r) need |= (tmax[r] > Mrun[r] + 11.0f) ? 1 : 0;
    if (__any(need)) {
#pragma unroll
      for (int r = 0; r < 4; ++r) {
        const float mnew = fmaxf(Mrun[r], tmax[r]);
        const float alpha = exp2f(Mrun[r] - mnew);
        Mrun[r] = mnew;
        lrun[r] *= alpha;
#pragma unroll
        for (int no = 0; no < 8; ++no) oacc[no][r] *= alpha;
      }
    }

    float tsum[4];
#pragma unroll
    for (int r = 0; r < 4; ++r) tsum[r] = 0.f;
#pragma unroll
    for (int n = 0; n < 4; ++n)
#pragma unroll
      for (int r = 0; r < 4; ++r) {
        const float p = exp2f(sacc[n][r] - Mrun[r]);   // bounded by 2^11
        tsum[r] += p;
        const int prow = wid * 16 + orow + r;
        Ps[prow][sw8(prow, n * 16 + ocol)] = f2bf(p);
      }
#pragma unroll
    for (int r = 0; r < 4; ++r) {
      float t = tsum[r];
      t += __shfl_xor(t, 1);
      t += __shfl_xor(t, 2);
      t += __shfl_xor(t, 4);
      t += __shfl_xor(t, 8);
      lrun[r] += t;
    }

    __syncthreads();  // P visible before PV (R4 lesson: required)

    __builtin_amdgcn_s_setprio(1);
#pragma unroll
    for (int kk = 0; kk < 2; ++kk) {
      const int prow = wid * 16 + frow;
      bf16x8_t pa = *reinterpret_cast<const bf16x8_t*>(&Ps[prow][sw8(prow, kk * 32 + fk8)]);
#pragma unroll
      for (int no = 0; no < 8; ++no) {
        const int vrow = no * 16 + frow;
        bf16x8_t bv = *reinterpret_cast<const bf16x8_t*>(&Vs[vrow][sw8(vrow, kk * 32 + fk8)]);
        oacc[no] = __builtin_amdgcn_mfma_f32_16x16x32_bf16(pa, bv, oacc[no], 0, 0, 0);
      }
    }
    __builtin_amdgcn_s_setprio(0);
  }

#pragma unroll
  for (int r = 0; r < 4; ++r) {
    const float rl = 1.0f / lrun[r];
    const long trow = qrow0 + orow + r;
#pragma unroll
    for (int no = 0; no < 8; ++no)
      Out[trow * (long)D + h * Dh + no * 16 + ocol] = f2bf(oacc[no][r] * rl);
  }
}

// ---- launch --------------------------------------------------------------

extern "C" void kernel_launch(void* const* d_in, const int* in_sizes, int n_in,
                              void* d_out, int out_size, void* d_ws, size_t ws_size,
                              hipStream_t stream) {
  const float* hs   = (const float*)d_in[0];
  const float* qkvw = (const float*)d_in[1];
  const float* ow   = (const float*)d_in[2];

  const int D = 2048, B = 2, H = 16;
  const long TD = (long)in_sizes[0];   // T*D = 8388608
  const long DD = (long)in_sizes[2];   // D*D = 4194304
  const int T = (int)(TD / D);         // 4096
  const int S = T / B;                 // 2048
  const int Dh = D / H;                // 128
  const float log2e = 1.44269504f;
  const float qs = (1.0f / sqrtf((float)Dh)) * log2e;  // Q prescale

  u16* ws  = (u16*)d_ws;
  u16* hsb = ws;                  // TD    (later reused as attn)
  u16* wt  = ws + TD;             // 3*DD  (later reused as vt)
  u16* owt = wt + 3 * DD;         // DD
  u16* qkv = owt + DD;            // 3*TD  [Q | K | V]
  u16* vt   = wt;                 // TD    (overlay; wt dead after QKV GEMM)
  u16* attn = hsb;                // TD    (overlay; hsb dead after QKV GEMM)

  // 1) hidden -> bf16
  k_cast_bf16<<<dim3((unsigned)(TD / 1024)), 256, 0, stream>>>(hs, hsb, TD);
  // 2) qkv weights: cast + transpose to [3][E][D] (== fused Bt [6144][2048])
  k_transpose_cast<<<dim3(D / 32, D / 32, 3), 256, 0, stream>>>(qkvw, wt, D, D);
  // 3) o_proj weight: cast + transpose to [E][D]
  k_transpose_cast<<<dim3(D / 32, D / 32, 1), 256, 0, stream>>>(ow, owt, D, D);
  // 4) fused QKV projection (k_gemm8, best measured 128.5us)
  k_gemm8<u16><<<dim3((3 * D) / 256, T / 256), 512, 0, stream>>>(
      hsb, wt, qkv, T, 3 * D, D, TD, qs);
  // 5) V -> Vt[bh][Dh][S]
  k_transpose_v<<<dim3(S / 32, Dh / 32, B * H), 256, 0, stream>>>(
      qkv + 2 * TD, vt, S, D, Dh, H);
  // 6) attention (QBLK=64, log2 domain, descending-k + defer-max)
  k_attn<<<dim3(S / 64, B * H), 256, 0, stream>>>(
      qkv, qkv + TD, vt, attn, B, S, H, D, log2e);
  // 7) output projection -> f32 d_out (128x256 tiles: 8x32 = 256 blocks = 1 round)
  k_gemm2<float><<<dim3(D / 256, T / 128), 512, 0, stream>>>(
      attn, owt, (float*)d_out, T, D, D, 0L, 1.0f);
}

// Round 14
// 290.103 us; speedup vs baseline: 1.6063x; 1.0123x over previous
//
#include <hip/hip_runtime.h>
#include <math.h>
#include <stdint.h>

typedef __bf16 bf16x8_t __attribute__((ext_vector_type(8)));
typedef float  f32x4_t  __attribute__((ext_vector_type(4)));
typedef unsigned short u16;

// ---- helpers -------------------------------------------------------------

__device__ __forceinline__ u16 f2bf(float f) {
  unsigned u = __float_as_uint(f);
  u += 0x7FFFu + ((u >> 16) & 1u);
  return (u16)(u >> 16);
}

// native bf16 convert (v_cvt_pk_bf16_f32, RNE) — 1 VALU op vs f2bf's 3
__device__ __forceinline__ u16 bf16bits(float f) {
  __bf16 b = (__bf16)f;
  return __builtin_bit_cast(u16, b);
}

__device__ __forceinline__ void gload_lds16(const u16* gsrc, u16* ldst) {
  // async global->LDS, 16B per lane; LDS dest = wave-uniform base + lane*16
  __builtin_amdgcn_global_load_lds(
      (__attribute__((address_space(1))) void*)(const_cast<u16*>(gsrc)),
      (__attribute__((address_space(3))) void*)(ldst),
      16, 0, 0);
}

// XOR swizzle for 128B rows (64 bf16): byte ^= ((row&7)<<4) == elem ^= ((row&7)<<3)
__device__ __forceinline__ int sw8(int row, int e) { return e ^ ((row & 7) << 3); }

__device__ __forceinline__ void store_out(float* C, long idx, float v) { C[idx] = v; }
__device__ __forceinline__ void store_out(u16* C, long idx, float v) { C[idx] = f2bf(v); }

__device__ __forceinline__ float alibi_slope(int h, int H) {
  int cp2 = 1, lg = 0;
  while (cp2 * 2 <= H) { cp2 *= 2; lg++; }
  if (h < cp2) {
    double e = exp2((double)-(lg - 3));
    return (float)exp2(-e * (double)(h + 1));
  } else {
    double e = exp2((double)-(lg + 1 - 3));
    return (float)exp2(-e * (double)(2 * (h - cp2) + 1));
  }
}

#define FENCE() asm volatile("" ::: "memory")
#define BARRIER() do { FENCE(); __builtin_amdgcn_s_barrier(); \
                       __builtin_amdgcn_sched_barrier(0); FENCE(); } while (0)
#define WAITLGKM() do { asm volatile("s_waitcnt lgkmcnt(0)" ::: "memory"); \
                        __builtin_amdgcn_sched_barrier(0); } while (0)

// ---- elementwise cast f32 -> bf16 ---------------------------------------

__global__ __launch_bounds__(256) void k_cast_bf16(const float* __restrict__ in,
                                                   u16* __restrict__ out, long n) {
  long i = ((long)blockIdx.x * 256 + threadIdx.x) * 4;
  if (i + 3 < n) {
    float4 v = *reinterpret_cast<const float4*>(in + i);
    ushort4 o;
    o.x = f2bf(v.x); o.y = f2bf(v.y); o.z = f2bf(v.z); o.w = f2bf(v.w);
    *reinterpret_cast<ushort4*>(out + i) = o;
  }
}

// ---- transpose + cast: out[z][c][r] = bf16(in[z][r][c]) ------------------

__global__ __launch_bounds__(256) void k_transpose_cast(const float* __restrict__ in,
                                                        u16* __restrict__ out,
                                                        int R, int C) {
  __shared__ float tile[32][33];
  const float* inz = in + (long)blockIdx.z * R * C;
  u16* outz = out + (long)blockIdx.z * R * C;
  const int tx = threadIdx.x & 31, ty = threadIdx.x >> 5;
  const int r0 = blockIdx.y * 32, c0 = blockIdx.x * 32;
#pragma unroll
  for (int i = 0; i < 4; ++i)
    tile[ty + i * 8][tx] = inz[(long)(r0 + ty + i * 8) * C + c0 + tx];
  __syncthreads();
#pragma unroll
  for (int i = 0; i < 4; ++i)
    outz[(long)(c0 + ty + i * 8) * R + r0 + tx] = f2bf(tile[tx][ty + i * 8]);
}

// ---- per-(b,h) transpose of V: [S,Dh slice of D] -> Vt[bh][Dh][S] --------

__global__ __launch_bounds__(256) void k_transpose_v(const u16* __restrict__ V,
                                                     u16* __restrict__ Vt,
                                                     int S, int D, int Dh, int H) {
  __shared__ u16 tile[32][33];
  const int bh = blockIdx.z, b = bh / H, h = bh % H;
  const int tx = threadIdx.x & 31, ty = threadIdx.x >> 5;
  const int s0 = blockIdx.x * 32, d0 = blockIdx.y * 32;
  const u16* vin = V + (long)b * S * D + (long)h * Dh;
#pragma unroll
  for (int i = 0; i < 4; ++i)
    tile[ty + i * 8][tx] = vin[(long)(s0 + ty + i * 8) * D + d0 + tx];
  __syncthreads();
  u16* vout = Vt + (long)bh * Dh * S;
#pragma unroll
  for (int i = 0; i < 4; ++i)
    vout[(long)(d0 + ty + i * 8) * S + s0 + tx] = tile[tx][ty + i * 8];
}

// ---- staging helpers (linear LDS dest + inverse-swizzled global source) --

__device__ __forceinline__ void stage16(const u16* __restrict__ g, long grow0, int K,
                                        int kt, int lr0, u16 (*lds)[64], int lane) {
  const int e = (lane & 7) * 8;
#pragma unroll
  for (int i = 0; i < 2; ++i) {
    const int r = lr0 + i * 8 + (lane >> 3);
    gload_lds16(g + (grow0 + r) * (long)K + kt + (e ^ ((r & 7) << 3)), &lds[lr0 + i * 8][0]);
  }
}

__device__ __forceinline__ void stage8(const u16* __restrict__ g, long grow0, int K,
                                       int kt, int lr0, u16 (*lds)[64], int lane) {
  const int e = (lane & 7) * 8;
  const int r = lr0 + (lane >> 3);
  gload_lds16(g + (grow0 + r) * (long)K + kt + (e ^ ((r & 7) << 3)), &lds[lr0][0]);
}

// ---- 256x256 4-phase bf16 GEMM (QKV; best measured: 128.5us R10) ---------

template <typename OUT_T>
__global__ __launch_bounds__(512, 2) void k_gemm8(const u16* __restrict__ A,
                                                  const u16* __restrict__ Bt,
                                                  OUT_T* __restrict__ Cb,
                                                  int M, int N, int K, long matStride,
                                                  float qs) {
  __shared__ u16 As[2][256][64];
  __shared__ u16 Bs[2][256][64];

  const int tid = threadIdx.x, wid = tid >> 6, lane = tid & 63;
  const int wr = wid >> 2, wc = wid & 3;
  const int frow = lane & 15, fk8 = (lane >> 4) * 8;
  const int orow = (lane >> 4) * 4, ocol = lane & 15;

  const int nwg = gridDim.x * gridDim.y;
  const int orig = blockIdx.y * gridDim.x + blockIdx.x;
  const int q = nwg >> 3, rr = nwg & 7;
  const int xcd = orig & 7, sl = orig >> 3;
  const int wg = (xcd < rr ? xcd * (q + 1) : rr * (q + 1) + (xcd - rr) * q) + sl;
  const int by = wg / gridDim.x, bx = wg % gridDim.x;

  const long abase = (long)by * 256, bbase = (long)bx * 256;

  const int bg0 = (wid >> 1) * 64 + (wid & 1) * 16;
  const int ag0 = (wid >> 2) * 128 + (wid & 3) * 16;

  f32x4_t acc[8][4];
#pragma unroll
  for (int m = 0; m < 8; ++m)
#pragma unroll
    for (int n = 0; n < 4; ++n)
#pragma unroll
      for (int r = 0; r < 4; ++r) acc[m][n][r] = 0.f;

  const int nt = K >> 6;

  stage16(A, abase, K, 0, ag0, As[0], lane);
  stage16(Bt, bbase, K, 0, bg0, Bs[0], lane);
  stage16(Bt, bbase, K, 0, bg0 + 32, Bs[0], lane);
  stage16(A, abase, K, 0, ag0 + 64, As[0], lane);
  asm volatile("s_waitcnt vmcnt(4)" ::: "memory");
  BARRIER();

  bf16x8_t afr[4][2], bfr[4][2];
  int cur = 0;

  for (int t = 0; t < nt; ++t) {
    const int ktn = (t + 1) << 6;
    const bool hn = (t + 1 < nt);
    const int nb = cur ^ 1;

    // ---- phase 1: quadrant (mh0,nh0); stage A-h0(t+1)
#pragma unroll
    for (int m = 0; m < 4; ++m) {
      const int r = wr * 128 + m * 16 + frow;
      afr[m][0] = *reinterpret_cast<const bf16x8_t*>(&As[cur][r][sw8(r, fk8)]);
      afr[m][1] = *reinterpret_cast<const bf16x8_t*>(&As[cur][r][sw8(r, 32 + fk8)]);
    }
#pragma unroll
    for (int n = 0; n < 2; ++n) {
      const int r = wc * 64 + n * 16 + frow;
      bfr[n][0] = *reinterpret_cast<const bf16x8_t*>(&Bs[cur][r][sw8(r, fk8)]);
      bfr[n][1] = *reinterpret_cast<const bf16x8_t*>(&Bs[cur][r][sw8(r, 32 + fk8)]);
    }
    if (hn) stage16(A, abase, K, ktn, ag0, As[nb], lane);
    BARRIER();
    WAITLGKM();
    __builtin_amdgcn_s_setprio(1);
#pragma unroll
    for (int m = 0; m < 4; ++m)
#pragma unroll
      for (int n = 0; n < 2; ++n) {
        acc[m][n] = __builtin_amdgcn_mfma_f32_16x16x32_bf16(afr[m][0], bfr[n][0], acc[m][n], 0, 0, 0);
        acc[m][n] = __builtin_amdgcn_mfma_f32_16x16x32_bf16(afr[m][1], bfr[n][1], acc[m][n], 0, 0, 0);
      }
    __builtin_amdgcn_s_setprio(0);
    if (hn) asm volatile("s_waitcnt vmcnt(4)" ::: "memory");
    else    asm volatile("s_waitcnt vmcnt(2)" ::: "memory");
    BARRIER();

    // ---- phase 2: quadrant (mh0,nh1); stage B-h0(t+1)
#pragma unroll
    for (int n = 0; n < 2; ++n) {
      const int r = wc * 64 + 32 + n * 16 + frow;
      bfr[2 + n][0] = *reinterpret_cast<const bf16x8_t*>(&Bs[cur][r][sw8(r, fk8)]);
      bfr[2 + n][1] = *reinterpret_cast<const bf16x8_t*>(&Bs[cur][r][sw8(r, 32 + fk8)]);
    }
    if (hn) stage16(Bt, bbase, K, ktn, bg0, Bs[nb], lane);
    BARRIER();
    WAITLGKM();
    __builtin_amdgcn_s_setprio(1);
#pragma unroll
    for (int m = 0; m < 4; ++m)
#pragma unroll
      for (int n = 0; n < 2; ++n) {
        acc[m][2 + n] = __builtin_amdgcn_mfma_f32_16x16x32_bf16(afr[m][0], bfr[2 + n][0], acc[m][2 + n], 0, 0, 0);
        acc[m][2 + n] = __builtin_amdgcn_mfma_f32_16x16x32_bf16(afr[m][1], bfr[2 + n][1], acc[m][2 + n], 0, 0, 0);
      }
    __builtin_amdgcn_s_setprio(0);
    if (!hn) asm volatile("s_waitcnt vmcnt(0)" ::: "memory");
    BARRIER();

    // ---- phase 3: quadrant (mh1,nh0); stage B-h1(t+1)
#pragma unroll
    for (int m = 0; m < 4; ++m) {
      const int r = wr * 128 + 64 + m * 16 + frow;
      afr[m][0] = *reinterpret_cast<const bf16x8_t*>(&As[cur][r][sw8(r, fk8)]);
      afr[m][1] = *reinterpret_cast<const bf16x8_t*>(&As[cur][r][sw8(r, 32 + fk8)]);
    }
    if (hn) stage16(Bt, bbase, K, ktn, bg0 + 32, Bs[nb], lane);
    BARRIER();
    WAITLGKM();
    __builtin_amdgcn_s_setprio(1);
#pragma unroll
    for (int m = 0; m < 4; ++m)
#pragma unroll
      for (int n = 0; n < 2; ++n) {
        acc[4 + m][n] = __builtin_amdgcn_mfma_f32_16x16x32_bf16(afr[m][0], bfr[n][0], acc[4 + m][n], 0, 0, 0);
        acc[4 + m][n] = __builtin_amdgcn_mfma_f32_16x16x32_bf16(afr[m][1], bfr[n][1], acc[4 + m][n], 0, 0, 0);
      }
    __builtin_amdgcn_s_setprio(0);
    BARRIER();

    // ---- phase 4: quadrant (mh1,nh1); stage A-h1(t+1)
    if (hn) stage16(A, abase, K, ktn, ag0 + 64, As[nb], lane);
    __builtin_amdgcn_s_setprio(1);
#pragma unroll
    for (int m = 0; m < 4; ++m)
#pragma unroll
      for (int n = 0; n < 2; ++n) {
        acc[4 + m][2 + n] = __builtin_amdgcn_mfma_f32_16x16x32_bf16(afr[m][0], bfr[2 + n][0], acc[4 + m][2 + n], 0, 0, 0);
        acc[4 + m][2 + n] = __builtin_amdgcn_mfma_f32_16x16x32_bf16(afr[m][1], bfr[2 + n][1], acc[4 + m][2 + n], 0, 0, 0);
      }
    __builtin_amdgcn_s_setprio(0);
    if (hn) asm volatile("s_waitcnt vmcnt(4)" ::: "memory");
    BARRIER();

    cur ^= 1;
  }

#pragma unroll
  for (int m = 0; m < 8; ++m)
#pragma unroll
    for (int n = 0; n < 4; ++n)
#pragma unroll
      for (int r = 0; r < 4; ++r) {
        const long row = abase + wr * 128 + m * 16 + orow + r;
        const int col = (int)bbase + wc * 64 + n * 16 + ocol;
        const float sc = ((col >> 11) == 0) ? qs : 1.0f;
        const long idx = (long)(col >> 11) * matStride + row * 2048 + (col & 2047);
        store_out(Cb, idx, acc[m][n][r] * sc);
      }
}

// ---- 128x256 2-phase bf16 GEMM (O-proj: 8x32 = 256 blocks = 1 round) -----

template <typename OUT_T>
__global__ __launch_bounds__(512, 2) void k_gemm2(const u16* __restrict__ A,
                                                  const u16* __restrict__ Bt,
                                                  OUT_T* __restrict__ Cb,
                                                  int M, int N, int K, long matStride,
                                                  float qs) {
  __shared__ u16 As[2][128][64];
  __shared__ u16 Bs[2][256][64];

  const int tid = threadIdx.x, wid = tid >> 6, lane = tid & 63;
  const int wr = wid >> 2, wc = wid & 3;
  const int frow = lane & 15, fk8 = (lane >> 4) * 8;
  const int orow = (lane >> 4) * 4, ocol = lane & 15;

  const int nwg = gridDim.x * gridDim.y;
  const int orig = blockIdx.y * gridDim.x + blockIdx.x;
  const int q = nwg >> 3, rr = nwg & 7;
  const int xcd = orig & 7, sl = orig >> 3;
  const int wg = (xcd < rr ? xcd * (q + 1) : rr * (q + 1) + (xcd - rr) * q) + sl;
  const int by = wg / gridDim.x, bx = wg % gridDim.x;

  const long abase = (long)by * 128, bbase = (long)bx * 256;

  const int bg0 = (wid >> 1) * 64 + (wid & 1) * 16;
  const int ag0 = ((wid & 1) << 6) + ((wid >> 1) << 3);

  f32x4_t acc[4][4];
#pragma unroll
  for (int m = 0; m < 4; ++m)
#pragma unroll
    for (int n = 0; n < 4; ++n)
#pragma unroll
      for (int r = 0; r < 4; ++r) acc[m][n][r] = 0.f;

  const int nt = K >> 6;

  stage16(Bt, bbase, K, 0, bg0, Bs[0], lane);
  stage16(Bt, bbase, K, 0, bg0 + 32, Bs[0], lane);
  stage8 (A,  abase, K, 0, ag0, As[0], lane);
  stage8 (A,  abase, K, 0, ag0 + 32, As[0], lane);
  asm volatile("s_waitcnt vmcnt(1)" ::: "memory");
  BARRIER();

  bf16x8_t bfr[4][2], afr[2][2];
  int cur = 0;

  for (int t = 0; t < nt; ++t) {
    const int ktn = (t + 1) << 6;
    const bool hn = (t + 1 < nt);
    const int nb = cur ^ 1;

#pragma unroll
    for (int n = 0; n < 4; ++n) {
      const int r = wc * 64 + n * 16 + frow;
      bfr[n][0] = *reinterpret_cast<const bf16x8_t*>(&Bs[cur][r][sw8(r, fk8)]);
      bfr[n][1] = *reinterpret_cast<const bf16x8_t*>(&Bs[cur][r][sw8(r, 32 + fk8)]);
    }
#pragma unroll
    for (int m = 0; m < 2; ++m) {
      const int r = wr * 64 + m * 16 + frow;
      afr[m][0] = *reinterpret_cast<const bf16x8_t*>(&As[cur][r][sw8(r, fk8)]);
      afr[m][1] = *reinterpret_cast<const bf16x8_t*>(&As[cur][r][sw8(r, 32 + fk8)]);
    }
    if (hn) {
      stage16(Bt, bbase, K, ktn, bg0, Bs[nb], lane);
      stage16(Bt, bbase, K, ktn, bg0 + 32, Bs[nb], lane);
    }
    BARRIER();
    WAITLGKM();
    __builtin_amdgcn_s_setprio(1);
#pragma unroll
    for (int m = 0; m < 2; ++m)
#pragma unroll
      for (int n = 0; n < 4; ++n) {
        acc[m][n] = __builtin_amdgcn_mfma_f32_16x16x32_bf16(afr[m][0], bfr[n][0], acc[m][n], 0, 0, 0);
        acc[m][n] = __builtin_amdgcn_mfma_f32_16x16x32_bf16(afr[m][1], bfr[n][1], acc[m][n], 0, 0, 0);
      }
    __builtin_amdgcn_s_setprio(0);
    if (hn) asm volatile("s_waitcnt vmcnt(4)" ::: "memory");
    else    asm volatile("s_waitcnt vmcnt(0)" ::: "memory");
    BARRIER();

#pragma unroll
    for (int m = 0; m < 2; ++m) {
      const int r = wr * 64 + 32 + m * 16 + frow;
      afr[m][0] = *reinterpret_cast<const bf16x8_t*>(&As[cur][r][sw8(r, fk8)]);
      afr[m][1] = *reinterpret_cast<const bf16x8_t*>(&As[cur][r][sw8(r, 32 + fk8)]);
    }
    if (hn) {
      stage8(A, abase, K, ktn, ag0, As[nb], lane);
      stage8(A, abase, K, ktn, ag0 + 32, As[nb], lane);
    }
    BARRIER();
    WAITLGKM();
    __builtin_amdgcn_s_setprio(1);
#pragma unroll
    for (int m = 0; m < 2; ++m)
#pragma unroll
      for (int n = 0; n < 4; ++n) {
        acc[2 + m][n] = __builtin_amdgcn_mfma_f32_16x16x32_bf16(afr[m][0], bfr[n][0], acc[2 + m][n], 0, 0, 0);
        acc[2 + m][n] = __builtin_amdgcn_mfma_f32_16x16x32_bf16(afr[m][1], bfr[n][1], acc[2 + m][n], 0, 0, 0);
      }
    __builtin_amdgcn_s_setprio(0);
    if (hn) asm volatile("s_waitcnt vmcnt(1)" ::: "memory");
    BARRIER();

    cur ^= 1;
  }

#pragma unroll
  for (int m = 0; m < 4; ++m)
#pragma unroll
    for (int n = 0; n < 4; ++n)
#pragma unroll
      for (int r = 0; r < 4; ++r) {
        const long row = abase + wr * 64 + m * 16 + orow + r;
        const int col = (int)bbase + wc * 64 + n * 16 + ocol;
        const float sc = ((col >> 11) == 0) ? qs : 1.0f;
        const long idx = (long)(col >> 11) * matStride + row * 2048 + (col & 2047);
        store_out(Cb, idx, acc[m][n][r] * sc);
      }
}

// ---- flash attention, QBLK=64, log2 softmax, DOUBLE-BUFFERED K/V ----------
// R14 (T3 minimum-2-phase): stage tile t-1 into buf^1 BEFORE computing
// tile t; mid Ps-barrier uses lgkmcnt(0)+s_barrier ONLY (no vmcnt drain ->
// staging loads stay in flight across it); one vmcnt(0)+barrier per tile
// at the end. LDS 72KB -> 2 blocks/CU. Descending-k + defer-max retained.
// Native bf16 cvt (bf16bits) replaces 3-op f2bf in the hot path.

__global__ __launch_bounds__(256) void k_attn(const u16* __restrict__ Q,
                                              const u16* __restrict__ Kb,
                                              const u16* __restrict__ Vt,
                                              u16* __restrict__ Out,
                                              int B, int S, int H, int D,
                                              float log2e) {
  __shared__ u16 Ks[2][64][128];   // 32KB dbuf (swizzled)
  __shared__ u16 Vs[2][128][64];   // 32KB dbuf (swizzled)
  __shared__ u16 Ps[64][64];       //  8KB

  const int tid = threadIdx.x, wid = tid >> 6, lane = tid & 63;

  const int nq = gridDim.x, nbh = gridDim.y;
  const int lin = blockIdx.x + nq * blockIdx.y;
  const int qb0 = lin / nbh;
  const int bh  = lin % nbh;
  const int qb  = (qb0 < nq / 2) ? qb0 : (nq + nq / 2 - 1 - qb0);

  const int b = bh / H, h = bh % H;
  const int Dh = D / H;

  const float slope2 = alibi_slope(h, H) * log2e;
  const long qrow0 = (long)b * S + qb * 64 + wid * 16;

  const int frow = lane & 15;
  const int fk8  = (lane >> 4) * 8;
  const int orow = (lane >> 4) * 4;
  const int ocol = lane & 15;

  bf16x8_t aq[4];
#pragma unroll
  for (int kk = 0; kk < 4; ++kk)
    aq[kk] = *reinterpret_cast<const bf16x8_t*>(
        Q + (qrow0 + frow) * (long)D + h * Dh + kk * 32 + fk8);

  float cw[4];
#pragma unroll
  for (int n = 0; n < 4; ++n) cw[n] = slope2 * (float)(n * 16 + ocol);

  f32x4_t oacc[8];
#pragma unroll
  for (int no = 0; no < 8; ++no)
#pragma unroll
    for (int r = 0; r < 4; ++r) oacc[no][r] = 0.f;

  float Mrun[4], lrun[4];
#pragma unroll
  for (int r = 0; r < 4; ++r) { Mrun[r] = -3.0e38f; lrun[r] = 0.f; }

  const u16* kbase = Kb + (long)b * S * D + h * Dh;
  const u16* vbase = Vt + (long)bh * Dh * S;

  auto STAGE = [&](int kt, int bi) {
#pragma unroll
    for (int i = 0; i < 4; ++i) {
      const int lr = i * 16 + wid * 4;
      const int r  = lr + (lane >> 4);
      gload_lds16(kbase + ((long)kt * 64 + r) * (long)D + sw8(r, (lane & 15) * 8),
                  &Ks[bi][lr][0]);
    }
#pragma unroll
    for (int i = 0; i < 4; ++i) {
      const int lr = i * 32 + wid * 8;
      const int r  = lr + (lane >> 3);
      gload_lds16(vbase + (long)r * S + kt * 64 + sw8(r, (lane & 7) * 8),
                  &Vs[bi][lr][0]);
    }
  };

  // prologue: stage the first (diagonal) tile
  STAGE(qb, 0);
  asm volatile("s_waitcnt vmcnt(0)" ::: "memory");
  BARRIER();

  int cur = 0;

  // descending k-tiles: diagonal (masked, largest ALiBi bias) first
  for (int kt = qb; kt >= 0; --kt) {
    // issue next tile's staging loads; they fly under this tile's compute
    if (kt > 0) STAGE(kt - 1, cur ^ 1);

    // S = Q K^T (16 x 64 per wave), log2 domain
    f32x4_t sacc[4];
#pragma unroll
    for (int n = 0; n < 4; ++n)
#pragma unroll
      for (int r = 0; r < 4; ++r) sacc[n][r] = 0.f;

    __builtin_amdgcn_s_setprio(1);
#pragma unroll
    for (int kk = 0; kk < 4; ++kk) {
      bf16x8_t bk[4];
#pragma unroll
      for (int n = 0; n < 4; ++n) {
        const int krow = n * 16 + frow;
        bk[n] = *reinterpret_cast<const bf16x8_t*>(&Ks[cur][krow][sw8(krow, kk * 32 + fk8)]);
      }
#pragma unroll
      for (int n = 0; n < 4; ++n)
        sacc[n] = __builtin_amdgcn_mfma_f32_16x16x32_bf16(aq[kk], bk[n], sacc[n], 0, 0, 0);
    }
    __builtin_amdgcn_s_setprio(0);

    const float tb = slope2 * (float)(kt << 6);
    float cbn[4];
#pragma unroll
    for (int n = 0; n < 4; ++n) cbn[n] = tb + cw[n];

    float tmax[4];
#pragma unroll
    for (int r = 0; r < 4; ++r) tmax[r] = -3.0e38f;

    if (kt == qb) {
#pragma unroll
      for (int n = 0; n < 4; ++n)
#pragma unroll
        for (int r = 0; r < 4; ++r) {
          float v = sacc[n][r] + cbn[n];
          v = (n * 16 + ocol <= wid * 16 + orow + r) ? v : -1.0e30f;
          sacc[n][r] = v;
          tmax[r] = fmaxf(tmax[r], v);
        }
    } else {
#pragma unroll
      for (int n = 0; n < 4; ++n)
#pragma unroll
        for (int r = 0; r < 4; ++r) {
          const float v = sacc[n][r] + cbn[n];
          sacc[n][r] = v;
          tmax[r] = fmaxf(tmax[r], v);
        }
    }
#pragma unroll
    for (int r = 0; r < 4; ++r) {
      float t = tmax[r];
      t = fmaxf(t, __shfl_xor(t, 1));
      t = fmaxf(t, __shfl_xor(t, 2));
      t = fmaxf(t, __shfl_xor(t, 4));
      t = fmaxf(t, __shfl_xor(t, 8));
      tmax[r] = t;
    }

    // defer-max (T13): skip O-rescale unless some row max grew past THR=11
    int need = 0;
#pragma unroll
    for (int r = 0; r < 4; ++r) need |= (tmax[r] > Mrun[r] + 11.0f) ? 1 : 0;
    if (__any(need)) {
#pragma unroll
      for (int r = 0; r < 4; ++r) {
        const float mnew = fmaxf(Mrun[r], tmax[r]);
        const float alpha = exp2f(Mrun[r] - mnew);
        Mrun[r] = mnew;
        lrun[r] *= alpha;
#pragma unroll
        for (int no = 0; no < 8; ++no) oacc[no][r] *= alpha;
      }
    }

    float tsum[4];
#pragma unroll
    for (int r = 0; r < 4; ++r) tsum[r] = 0.f;
#pragma unroll
    for (int n = 0; n < 4; ++n)
#pragma unroll
      for (int r = 0; r < 4; ++r) {
        const float p = exp2f(sacc[n][r] - Mrun[r]);   // bounded by 2^11
        tsum[r] += p;
        const int prow = wid * 16 + orow + r;
        Ps[prow][sw8(prow, n * 16 + ocol)] = bf16bits(p);
      }
#pragma unroll
    for (int r = 0; r < 4; ++r) {
      float t = tsum[r];
      t += __shfl_xor(t, 1);
      t += __shfl_xor(t, 2);
      t += __shfl_xor(t, 4);
      t += __shfl_xor(t, 8);
      lrun[r] += t;
    }

    // mid barrier: Ps visible to all waves. lgkmcnt only — staging loads
    // (vmcnt) deliberately stay in flight (R4 lesson: barrier itself stays).
    WAITLGKM();
    BARRIER();

    __builtin_amdgcn_s_setprio(1);
#pragma unroll
    for (int kk = 0; kk < 2; ++kk) {
      const int prow = wid * 16 + frow;
      bf16x8_t pa = *reinterpret_cast<const bf16x8_t*>(&Ps[prow][sw8(prow, kk * 32 + fk8)]);
#pragma unroll
      for (int no = 0; no < 8; ++no) {
        const int vrow = no * 16 + frow;
        bf16x8_t bv = *reinterpret_cast<const bf16x8_t*>(&Vs[cur][vrow][sw8(vrow, kk * 32 + fk8)]);
        oacc[no] = __builtin_amdgcn_mfma_f32_16x16x32_bf16(pa, bv, oacc[no], 0, 0, 0);
      }
    }
    __builtin_amdgcn_s_setprio(0);

    // tile end: land next tile's loads; all waves done reading cur & Ps
    if (kt > 0) {
      asm volatile("s_waitcnt vmcnt(0)" ::: "memory");
      BARRIER();
      cur ^= 1;
    }
  }

#pragma unroll
  for (int r = 0; r < 4; ++r) {
    const float rl = 1.0f / lrun[r];
    const long trow = qrow0 + orow + r;
#pragma unroll
    for (int no = 0; no < 8; ++no)
      Out[trow * (long)D + h * Dh + no * 16 + ocol] = bf16bits(oacc[no][r] * rl);
  }
}

// ---- launch --------------------------------------------------------------

extern "C" void kernel_launch(void* const* d_in, const int* in_sizes, int n_in,
                              void* d_out, int out_size, void* d_ws, size_t ws_size,
                              hipStream_t stream) {
  const float* hs   = (const float*)d_in[0];
  const float* qkvw = (const float*)d_in[1];
  const float* ow   = (const float*)d_in[2];

  const int D = 2048, B = 2, H = 16;
  const long TD = (long)in_sizes[0];   // T*D = 8388608
  const long DD = (long)in_sizes[2];   // D*D = 4194304
  const int T = (int)(TD / D);         // 4096
  const int S = T / B;                 // 2048
  const int Dh = D / H;                // 128
  const float log2e = 1.44269504f;
  const float qs = (1.0f / sqrtf((float)Dh)) * log2e;  // Q prescale

  u16* ws  = (u16*)d_ws;
  u16* hsb = ws;                  // TD    (later reused as attn)
  u16* wt  = ws + TD;             // 3*DD  (later reused as vt)
  u16* owt = wt + 3 * DD;         // DD
  u16* qkv = owt + DD;            // 3*TD  [Q | K | V]
  u16* vt   = wt;                 // TD    (overlay; wt dead after QKV GEMM)
  u16* attn = hsb;                // TD    (overlay; hsb dead after QKV GEMM)

  // 1) hidden -> bf16
  k_cast_bf16<<<dim3((unsigned)(TD / 1024)), 256, 0, stream>>>(hs, hsb, TD);
  // 2) qkv weights: cast + transpose to [3][E][D] (== fused Bt [6144][2048])
  k_transpose_cast<<<dim3(D / 32, D / 32, 3), 256, 0, stream>>>(qkvw, wt, D, D);
  // 3) o_proj weight: cast + transpose to [E][D]
  k_transpose_cast<<<dim3(D / 32, D / 32, 1), 256, 0, stream>>>(ow, owt, D, D);
  // 4) fused QKV projection (k_gemm8, best measured 128.5us)
  k_gemm8<u16><<<dim3((3 * D) / 256, T / 256), 512, 0, stream>>>(
      hsb, wt, qkv, T, 3 * D, D, TD, qs);
  // 5) V -> Vt[bh][Dh][S]
  k_transpose_v<<<dim3(S / 32, Dh / 32, B * H), 256, 0, stream>>>(
      qkv + 2 * TD, vt, S, D, Dh, H);
  // 6) attention (QBLK=64, log2 domain, descending-k + defer-max + K/V dbuf)
  k_attn<<<dim3(S / 64, B * H), 256, 0, stream>>>(
      qkv, qkv + TD, vt, attn, B, S, H, D, log2e);
  // 7) output projection -> f32 d_out (128x256 tiles: 8x32 = 256 blocks = 1 round)
  k_gemm2<float><<<dim3(D / 256, T / 128), 512, 0, stream>>>(
      attn, owt, (float*)d_out, T, D, D, 0L, 1.0f);
}

// Round 15
// 283.637 us; speedup vs baseline: 1.6429x; 1.0228x over previous
//
#include <hip/hip_runtime.h>
#include <math.h>
#include <stdint.h>

typedef __bf16 bf16x8_t __attribute__((ext_vector_type(8)));
typedef float  f32x4_t  __attribute__((ext_vector_type(4)));
typedef unsigned short u16;

// ---- helpers -------------------------------------------------------------

__device__ __forceinline__ u16 f2bf(float f) {
  unsigned u = __float_as_uint(f);
  u += 0x7FFFu + ((u >> 16) & 1u);
  return (u16)(u >> 16);
}

// native bf16 convert (RNE) — 1 VALU op vs f2bf's 3
__device__ __forceinline__ u16 bf16bits(float f) {
  __bf16 b = (__bf16)f;
  return __builtin_bit_cast(u16, b);
}

__device__ __forceinline__ void gload_lds16(const u16* gsrc, u16* ldst) {
  // async global->LDS, 16B per lane; LDS dest = wave-uniform base + lane*16
  __builtin_amdgcn_global_load_lds(
      (__attribute__((address_space(1))) void*)(const_cast<u16*>(gsrc)),
      (__attribute__((address_space(3))) void*)(ldst),
      16, 0, 0);
}

// XOR swizzle for 128B rows (64 bf16): byte ^= ((row&7)<<4) == elem ^= ((row&7)<<3)
__device__ __forceinline__ int sw8(int row, int e) { return e ^ ((row & 7) << 3); }

__device__ __forceinline__ void store_out(float* C, long idx, float v) { C[idx] = v; }
__device__ __forceinline__ void store_out(u16* C, long idx, float v) { C[idx] = f2bf(v); }

__device__ __forceinline__ float alibi_slope(int h, int H) {
  int cp2 = 1, lg = 0;
  while (cp2 * 2 <= H) { cp2 *= 2; lg++; }
  if (h < cp2) {
    double e = exp2((double)-(lg - 3));
    return (float)exp2(-e * (double)(h + 1));
  } else {
    double e = exp2((double)-(lg + 1 - 3));
    return (float)exp2(-e * (double)(2 * (h - cp2) + 1));
  }
}

#define FENCE() asm volatile("" ::: "memory")
#define BARRIER() do { FENCE(); __builtin_amdgcn_s_barrier(); \
                       __builtin_amdgcn_sched_barrier(0); FENCE(); } while (0)
#define WAITLGKM() do { asm volatile("s_waitcnt lgkmcnt(0)" ::: "memory"); \
                        __builtin_amdgcn_sched_barrier(0); } while (0)

// ---- elementwise cast f32 -> bf16 ---------------------------------------

__global__ __launch_bounds__(256) void k_cast_bf16(const float* __restrict__ in,
                                                   u16* __restrict__ out, long n) {
  long i = ((long)blockIdx.x * 256 + threadIdx.x) * 4;
  if (i + 3 < n) {
    float4 v = *reinterpret_cast<const float4*>(in + i);
    ushort4 o;
    o.x = f2bf(v.x); o.y = f2bf(v.y); o.z = f2bf(v.z); o.w = f2bf(v.w);
    *reinterpret_cast<ushort4*>(out + i) = o;
  }
}

// ---- transpose + cast (merged): z<3 -> qkvw[z], z==3 -> ow ----------------
// out[z][c][r] = bf16(in_z[r][c]); out regions contiguous (owt = wt + 3*DD).

__global__ __launch_bounds__(256) void k_transpose_cast4(const float* __restrict__ in0,
                                                         const float* __restrict__ in1,
                                                         u16* __restrict__ out,
                                                         int R, int C) {
  __shared__ float tile[32][33];
  const float* inz = (blockIdx.z < 3) ? (in0 + (long)blockIdx.z * R * C) : in1;
  u16* outz = out + (long)blockIdx.z * R * C;
  const int tx = threadIdx.x & 31, ty = threadIdx.x >> 5;
  const int r0 = blockIdx.y * 32, c0 = blockIdx.x * 32;
#pragma unroll
  for (int i = 0; i < 4; ++i)
    tile[ty + i * 8][tx] = inz[(long)(r0 + ty + i * 8) * C + c0 + tx];
  __syncthreads();
#pragma unroll
  for (int i = 0; i < 4; ++i)
    outz[(long)(c0 + ty + i * 8) * R + r0 + tx] = f2bf(tile[tx][ty + i * 8]);
}

// ---- staging helpers (linear LDS dest + inverse-swizzled global source) --

__device__ __forceinline__ void stage16(const u16* __restrict__ g, long grow0, int K,
                                        int kt, int lr0, u16 (*lds)[64], int lane) {
  const int e = (lane & 7) * 8;
#pragma unroll
  for (int i = 0; i < 2; ++i) {
    const int r = lr0 + i * 8 + (lane >> 3);
    gload_lds16(g + (grow0 + r) * (long)K + kt + (e ^ ((r & 7) << 3)), &lds[lr0 + i * 8][0]);
  }
}

__device__ __forceinline__ void stage8(const u16* __restrict__ g, long grow0, int K,
                                       int kt, int lr0, u16 (*lds)[64], int lane) {
  const int e = (lane & 7) * 8;
  const int r = lr0 + (lane >> 3);
  gload_lds16(g + (grow0 + r) * (long)K + kt + (e ^ ((r & 7) << 3)), &lds[lr0][0]);
}

// ---- 256x256 4-phase bf16 GEMM (QKV; best measured: 128.5us R10) ---------
// Fused V-transpose epilogue: mat = bbase>>11 is block-uniform (2048%256==0).
// mat==2 (V) blocks write Vt[bh][Dh][S] layout directly into the V region.

template <typename OUT_T>
__global__ __launch_bounds__(512, 2) void k_gemm8(const u16* __restrict__ A,
                                                  const u16* __restrict__ Bt,
                                                  OUT_T* __restrict__ Cb,
                                                  int M, int N, int K, long matStride,
                                                  float qs, u16* __restrict__ Vt) {
  __shared__ u16 As[2][256][64];
  __shared__ u16 Bs[2][256][64];

  const int tid = threadIdx.x, wid = tid >> 6, lane = tid & 63;
  const int wr = wid >> 2, wc = wid & 3;
  const int frow = lane & 15, fk8 = (lane >> 4) * 8;
  const int orow = (lane >> 4) * 4, ocol = lane & 15;

  const int nwg = gridDim.x * gridDim.y;
  const int orig = blockIdx.y * gridDim.x + blockIdx.x;
  const int q = nwg >> 3, rr = nwg & 7;
  const int xcd = orig & 7, sl = orig >> 3;
  const int wg = (xcd < rr ? xcd * (q + 1) : rr * (q + 1) + (xcd - rr) * q) + sl;
  const int by = wg / gridDim.x, bx = wg % gridDim.x;

  const long abase = (long)by * 256, bbase = (long)bx * 256;

  const int bg0 = (wid >> 1) * 64 + (wid & 1) * 16;
  const int ag0 = (wid >> 2) * 128 + (wid & 3) * 16;

  f32x4_t acc[8][4];
#pragma unroll
  for (int m = 0; m < 8; ++m)
#pragma unroll
    for (int n = 0; n < 4; ++n)
#pragma unroll
      for (int r = 0; r < 4; ++r) acc[m][n][r] = 0.f;

  const int nt = K >> 6;

  stage16(A, abase, K, 0, ag0, As[0], lane);
  stage16(Bt, bbase, K, 0, bg0, Bs[0], lane);
  stage16(Bt, bbase, K, 0, bg0 + 32, Bs[0], lane);
  stage16(A, abase, K, 0, ag0 + 64, As[0], lane);
  asm volatile("s_waitcnt vmcnt(4)" ::: "memory");
  BARRIER();

  bf16x8_t afr[4][2], bfr[4][2];
  int cur = 0;

  for (int t = 0; t < nt; ++t) {
    const int ktn = (t + 1) << 6;
    const bool hn = (t + 1 < nt);
    const int nb = cur ^ 1;

    // ---- phase 1: quadrant (mh0,nh0); stage A-h0(t+1)
#pragma unroll
    for (int m = 0; m < 4; ++m) {
      const int r = wr * 128 + m * 16 + frow;
      afr[m][0] = *reinterpret_cast<const bf16x8_t*>(&As[cur][r][sw8(r, fk8)]);
      afr[m][1] = *reinterpret_cast<const bf16x8_t*>(&As[cur][r][sw8(r, 32 + fk8)]);
    }
#pragma unroll
    for (int n = 0; n < 2; ++n) {
      const int r = wc * 64 + n * 16 + frow;
      bfr[n][0] = *reinterpret_cast<const bf16x8_t*>(&Bs[cur][r][sw8(r, fk8)]);
      bfr[n][1] = *reinterpret_cast<const bf16x8_t*>(&Bs[cur][r][sw8(r, 32 + fk8)]);
    }
    if (hn) stage16(A, abase, K, ktn, ag0, As[nb], lane);
    BARRIER();
    WAITLGKM();
    __builtin_amdgcn_s_setprio(1);
#pragma unroll
    for (int m = 0; m < 4; ++m)
#pragma unroll
      for (int n = 0; n < 2; ++n) {
        acc[m][n] = __builtin_amdgcn_mfma_f32_16x16x32_bf16(afr[m][0], bfr[n][0], acc[m][n], 0, 0, 0);
        acc[m][n] = __builtin_amdgcn_mfma_f32_16x16x32_bf16(afr[m][1], bfr[n][1], acc[m][n], 0, 0, 0);
      }
    __builtin_amdgcn_s_setprio(0);
    if (hn) asm volatile("s_waitcnt vmcnt(4)" ::: "memory");
    else    asm volatile("s_waitcnt vmcnt(2)" ::: "memory");
    BARRIER();

    // ---- phase 2: quadrant (mh0,nh1); stage B-h0(t+1)
#pragma unroll
    for (int n = 0; n < 2; ++n) {
      const int r = wc * 64 + 32 + n * 16 + frow;
      bfr[2 + n][0] = *reinterpret_cast<const bf16x8_t*>(&Bs[cur][r][sw8(r, fk8)]);
      bfr[2 + n][1] = *reinterpret_cast<const bf16x8_t*>(&Bs[cur][r][sw8(r, 32 + fk8)]);
    }
    if (hn) stage16(Bt, bbase, K, ktn, bg0, Bs[nb], lane);
    BARRIER();
    WAITLGKM();
    __builtin_amdgcn_s_setprio(1);
#pragma unroll
    for (int m = 0; m < 4; ++m)
#pragma unroll
      for (int n = 0; n < 2; ++n) {
        acc[m][2 + n] = __builtin_amdgcn_mfma_f32_16x16x32_bf16(afr[m][0], bfr[2 + n][0], acc[m][2 + n], 0, 0, 0);
        acc[m][2 + n] = __builtin_amdgcn_mfma_f32_16x16x32_bf16(afr[m][1], bfr[2 + n][1], acc[m][2 + n], 0, 0, 0);
      }
    __builtin_amdgcn_s_setprio(0);
    if (!hn) asm volatile("s_waitcnt vmcnt(0)" ::: "memory");
    BARRIER();

    // ---- phase 3: quadrant (mh1,nh0); stage B-h1(t+1)
#pragma unroll
    for (int m = 0; m < 4; ++m) {
      const int r = wr * 128 + 64 + m * 16 + frow;
      afr[m][0] = *reinterpret_cast<const bf16x8_t*>(&As[cur][r][sw8(r, fk8)]);
      afr[m][1] = *reinterpret_cast<const bf16x8_t*>(&As[cur][r][sw8(r, 32 + fk8)]);
    }
    if (hn) stage16(Bt, bbase, K, ktn, bg0 + 32, Bs[nb], lane);
    BARRIER();
    WAITLGKM();
    __builtin_amdgcn_s_setprio(1);
#pragma unroll
    for (int m = 0; m < 4; ++m)
#pragma unroll
      for (int n = 0; n < 2; ++n) {
        acc[4 + m][n] = __builtin_amdgcn_mfma_f32_16x16x32_bf16(afr[m][0], bfr[n][0], acc[4 + m][n], 0, 0, 0);
        acc[4 + m][n] = __builtin_amdgcn_mfma_f32_16x16x32_bf16(afr[m][1], bfr[n][1], acc[4 + m][n], 0, 0, 0);
      }
    __builtin_amdgcn_s_setprio(0);
    BARRIER();

    // ---- phase 4: quadrant (mh1,nh1); stage A-h1(t+1)
    if (hn) stage16(A, abase, K, ktn, ag0 + 64, As[nb], lane);
    __builtin_amdgcn_s_setprio(1);
#pragma unroll
    for (int m = 0; m < 4; ++m)
#pragma unroll
      for (int n = 0; n < 2; ++n) {
        acc[4 + m][2 + n] = __builtin_amdgcn_mfma_f32_16x16x32_bf16(afr[m][0], bfr[2 + n][0], acc[4 + m][2 + n], 0, 0, 0);
        acc[4 + m][2 + n] = __builtin_amdgcn_mfma_f32_16x16x32_bf16(afr[m][1], bfr[2 + n][1], acc[4 + m][2 + n], 0, 0, 0);
      }
    __builtin_amdgcn_s_setprio(0);
    if (hn) asm volatile("s_waitcnt vmcnt(4)" ::: "memory");
    BARRIER();

    cur ^= 1;
  }

  const int mat = (int)(bbase >> 11);   // block-uniform (2048 % 256 == 0)
  if (Vt != nullptr && mat == 2) {
    // V block: write directly in Vt[bh = b*16+h][d][s] layout
#pragma unroll
    for (int m = 0; m < 8; ++m)
#pragma unroll
      for (int n = 0; n < 4; ++n)
#pragma unroll
        for (int r = 0; r < 4; ++r) {
          const long row = abase + wr * 128 + m * 16 + orow + r;  // token index
          const int col = (int)bbase + wc * 64 + n * 16 + ocol;
          const int e = col & 2047, hh = e >> 7, dd = e & 127;
          const long bb = row >> 11, ss = row & 2047;
          Vt[(((bb << 4) + hh) * 128 + dd) * 2048 + ss] = bf16bits(acc[m][n][r]);
        }
  } else {
#pragma unroll
    for (int m = 0; m < 8; ++m)
#pragma unroll
      for (int n = 0; n < 4; ++n)
#pragma unroll
        for (int r = 0; r < 4; ++r) {
          const long row = abase + wr * 128 + m * 16 + orow + r;
          const int col = (int)bbase + wc * 64 + n * 16 + ocol;
          const float sc = (mat == 0) ? qs : 1.0f;
          const long idx = (long)mat * matStride + row * 2048 + (col & 2047);
          store_out(Cb, idx, acc[m][n][r] * sc);
        }
  }
}

// ---- 128x256 2-phase bf16 GEMM (O-proj: 8x32 = 256 blocks = 1 round) -----

template <typename OUT_T>
__global__ __launch_bounds__(512, 2) void k_gemm2(const u16* __restrict__ A,
                                                  const u16* __restrict__ Bt,
                                                  OUT_T* __restrict__ Cb,
                                                  int M, int N, int K, long matStride,
                                                  float qs) {
  __shared__ u16 As[2][128][64];
  __shared__ u16 Bs[2][256][64];

  const int tid = threadIdx.x, wid = tid >> 6, lane = tid & 63;
  const int wr = wid >> 2, wc = wid & 3;
  const int frow = lane & 15, fk8 = (lane >> 4) * 8;
  const int orow = (lane >> 4) * 4, ocol = lane & 15;

  const int nwg = gridDim.x * gridDim.y;
  const int orig = blockIdx.y * gridDim.x + blockIdx.x;
  const int q = nwg >> 3, rr = nwg & 7;
  const int xcd = orig & 7, sl = orig >> 3;
  const int wg = (xcd < rr ? xcd * (q + 1) : rr * (q + 1) + (xcd - rr) * q) + sl;
  const int by = wg / gridDim.x, bx = wg % gridDim.x;

  const long abase = (long)by * 128, bbase = (long)bx * 256;

  const int bg0 = (wid >> 1) * 64 + (wid & 1) * 16;
  const int ag0 = ((wid & 1) << 6) + ((wid >> 1) << 3);

  f32x4_t acc[4][4];
#pragma unroll
  for (int m = 0; m < 4; ++m)
#pragma unroll
    for (int n = 0; n < 4; ++n)
#pragma unroll
      for (int r = 0; r < 4; ++r) acc[m][n][r] = 0.f;

  const int nt = K >> 6;

  stage16(Bt, bbase, K, 0, bg0, Bs[0], lane);
  stage16(Bt, bbase, K, 0, bg0 + 32, Bs[0], lane);
  stage8 (A,  abase, K, 0, ag0, As[0], lane);
  stage8 (A,  abase, K, 0, ag0 + 32, As[0], lane);
  asm volatile("s_waitcnt vmcnt(1)" ::: "memory");
  BARRIER();

  bf16x8_t bfr[4][2], afr[2][2];
  int cur = 0;

  for (int t = 0; t < nt; ++t) {
    const int ktn = (t + 1) << 6;
    const bool hn = (t + 1 < nt);
    const int nb = cur ^ 1;

#pragma unroll
    for (int n = 0; n < 4; ++n) {
      const int r = wc * 64 + n * 16 + frow;
      bfr[n][0] = *reinterpret_cast<const bf16x8_t*>(&Bs[cur][r][sw8(r, fk8)]);
      bfr[n][1] = *reinterpret_cast<const bf16x8_t*>(&Bs[cur][r][sw8(r, 32 + fk8)]);
    }
#pragma unroll
    for (int m = 0; m < 2; ++m) {
      const int r = wr * 64 + m * 16 + frow;
      afr[m][0] = *reinterpret_cast<const bf16x8_t*>(&As[cur][r][sw8(r, fk8)]);
      afr[m][1] = *reinterpret_cast<const bf16x8_t*>(&As[cur][r][sw8(r, 32 + fk8)]);
    }
    if (hn) {
      stage16(Bt, bbase, K, ktn, bg0, Bs[nb], lane);
      stage16(Bt, bbase, K, ktn, bg0 + 32, Bs[nb], lane);
    }
    BARRIER();
    WAITLGKM();
    __builtin_amdgcn_s_setprio(1);
#pragma unroll
    for (int m = 0; m < 2; ++m)
#pragma unroll
      for (int n = 0; n < 4; ++n) {
        acc[m][n] = __builtin_amdgcn_mfma_f32_16x16x32_bf16(afr[m][0], bfr[n][0], acc[m][n], 0, 0, 0);
        acc[m][n] = __builtin_amdgcn_mfma_f32_16x16x32_bf16(afr[m][1], bfr[n][1], acc[m][n], 0, 0, 0);
      }
    __builtin_amdgcn_s_setprio(0);
    if (hn) asm volatile("s_waitcnt vmcnt(4)" ::: "memory");
    else    asm volatile("s_waitcnt vmcnt(0)" ::: "memory");
    BARRIER();

#pragma unroll
    for (int m = 0; m < 2; ++m) {
      const int r = wr * 64 + 32 + m * 16 + frow;
      afr[m][0] = *reinterpret_cast<const bf16x8_t*>(&As[cur][r][sw8(r, fk8)]);
      afr[m][1] = *reinterpret_cast<const bf16x8_t*>(&As[cur][r][sw8(r, 32 + fk8)]);
    }
    if (hn) {
      stage8(A, abase, K, ktn, ag0, As[nb], lane);
      stage8(A, abase, K, ktn, ag0 + 32, As[nb], lane);
    }
    BARRIER();
    WAITLGKM();
    __builtin_amdgcn_s_setprio(1);
#pragma unroll
    for (int m = 0; m < 2; ++m)
#pragma unroll
      for (int n = 0; n < 4; ++n) {
        acc[2 + m][n] = __builtin_amdgcn_mfma_f32_16x16x32_bf16(afr[m][0], bfr[n][0], acc[2 + m][n], 0, 0, 0);
        acc[2 + m][n] = __builtin_amdgcn_mfma_f32_16x16x32_bf16(afr[m][1], bfr[n][1], acc[2 + m][n], 0, 0, 0);
      }
    __builtin_amdgcn_s_setprio(0);
    if (hn) asm volatile("s_waitcnt vmcnt(1)" ::: "memory");
    BARRIER();

    cur ^= 1;
  }

#pragma unroll
  for (int m = 0; m < 4; ++m)
#pragma unroll
    for (int n = 0; n < 4; ++n)
#pragma unroll
      for (int r = 0; r < 4; ++r) {
        const long row = abase + wr * 64 + m * 16 + orow + r;
        const int col = (int)bbase + wc * 64 + n * 16 + ocol;
        const float sc = ((col >> 11) == 0) ? qs : 1.0f;
        const long idx = (long)(col >> 11) * matStride + row * 2048 + (col & 2047);
        store_out(Cb, idx, acc[m][n][r] * sc);
      }
}

// ---- flash attention, QBLK=64, log2 softmax, double-buffered K/V (R14) ---

__global__ __launch_bounds__(256) void k_attn(const u16* __restrict__ Q,
                                              const u16* __restrict__ Kb,
                                              const u16* __restrict__ Vt,
                                              u16* __restrict__ Out,
                                              int B, int S, int H, int D,
                                              float log2e) {
  __shared__ u16 Ks[2][64][128];
  __shared__ u16 Vs[2][128][64];
  __shared__ u16 Ps[64][64];

  const int tid = threadIdx.x, wid = tid >> 6, lane = tid & 63;

  const int nq = gridDim.x, nbh = gridDim.y;
  const int lin = blockIdx.x + nq * blockIdx.y;
  const int qb0 = lin / nbh;
  const int bh  = lin % nbh;
  const int qb  = (qb0 < nq / 2) ? qb0 : (nq + nq / 2 - 1 - qb0);

  const int b = bh / H, h = bh % H;
  const int Dh = D / H;

  const float slope2 = alibi_slope(h, H) * log2e;
  const long qrow0 = (long)b * S + qb * 64 + wid * 16;

  const int frow = lane & 15;
  const int fk8  = (lane >> 4) * 8;
  const int orow = (lane >> 4) * 4;
  const int ocol = lane & 15;

  bf16x8_t aq[4];
#pragma unroll
  for (int kk = 0; kk < 4; ++kk)
    aq[kk] = *reinterpret_cast<const bf16x8_t*>(
        Q + (qrow0 + frow) * (long)D + h * Dh + kk * 32 + fk8);

  float cw[4];
#pragma unroll
  for (int n = 0; n < 4; ++n) cw[n] = slope2 * (float)(n * 16 + ocol);

  f32x4_t oacc[8];
#pragma unroll
  for (int no = 0; no < 8; ++no)
#pragma unroll
    for (int r = 0; r < 4; ++r) oacc[no][r] = 0.f;

  float Mrun[4], lrun[4];
#pragma unroll
  for (int r = 0; r < 4; ++r) { Mrun[r] = -3.0e38f; lrun[r] = 0.f; }

  const u16* kbase = Kb + (long)b * S * D + h * Dh;
  const u16* vbase = Vt + (long)bh * Dh * S;

  auto STAGE = [&](int kt, int bi) {
#pragma unroll
    for (int i = 0; i < 4; ++i) {
      const int lr = i * 16 + wid * 4;
      const int r  = lr + (lane >> 4);
      gload_lds16(kbase + ((long)kt * 64 + r) * (long)D + sw8(r, (lane & 15) * 8),
                  &Ks[bi][lr][0]);
    }
#pragma unroll
    for (int i = 0; i < 4; ++i) {
      const int lr = i * 32 + wid * 8;
      const int r  = lr + (lane >> 3);
      gload_lds16(vbase + (long)r * S + kt * 64 + sw8(r, (lane & 7) * 8),
                  &Vs[bi][lr][0]);
    }
  };

  STAGE(qb, 0);
  asm volatile("s_waitcnt vmcnt(0)" ::: "memory");
  BARRIER();

  int cur = 0;

  for (int kt = qb; kt >= 0; --kt) {
    if (kt > 0) STAGE(kt - 1, cur ^ 1);

    f32x4_t sacc[4];
#pragma unroll
    for (int n = 0; n < 4; ++n)
#pragma unroll
      for (int r = 0; r < 4; ++r) sacc[n][r] = 0.f;

    __builtin_amdgcn_s_setprio(1);
#pragma unroll
    for (int kk = 0; kk < 4; ++kk) {
      bf16x8_t bk[4];
#pragma unroll
      for (int n = 0; n < 4; ++n) {
        const int krow = n * 16 + frow;
        bk[n] = *reinterpret_cast<const bf16x8_t*>(&Ks[cur][krow][sw8(krow, kk * 32 + fk8)]);
      }
#pragma unroll
      for (int n = 0; n < 4; ++n)
        sacc[n] = __builtin_amdgcn_mfma_f32_16x16x32_bf16(aq[kk], bk[n], sacc[n], 0, 0, 0);
    }
    __builtin_amdgcn_s_setprio(0);

    const float tb = slope2 * (float)(kt << 6);
    float cbn[4];
#pragma unroll
    for (int n = 0; n < 4; ++n) cbn[n] = tb + cw[n];

    float tmax[4];
#pragma unroll
    for (int r = 0; r < 4; ++r) tmax[r] = -3.0e38f;

    if (kt == qb) {
#pragma unroll
      for (int n = 0; n < 4; ++n)
#pragma unroll
        for (int r = 0; r < 4; ++r) {
          float v = sacc[n][r] + cbn[n];
          v = (n * 16 + ocol <= wid * 16 + orow + r) ? v : -1.0e30f;
          sacc[n][r] = v;
          tmax[r] = fmaxf(tmax[r], v);
        }
    } else {
#pragma unroll
      for (int n = 0; n < 4; ++n)
#pragma unroll
        for (int r = 0; r < 4; ++r) {
          const float v = sacc[n][r] + cbn[n];
          sacc[n][r] = v;
          tmax[r] = fmaxf(tmax[r], v);
        }
    }
#pragma unroll
    for (int r = 0; r < 4; ++r) {
      float t = tmax[r];
      t = fmaxf(t, __shfl_xor(t, 1));
      t = fmaxf(t, __shfl_xor(t, 2));
      t = fmaxf(t, __shfl_xor(t, 4));
      t = fmaxf(t, __shfl_xor(t, 8));
      tmax[r] = t;
    }

    int need = 0;
#pragma unroll
    for (int r = 0; r < 4; ++r) need |= (tmax[r] > Mrun[r] + 11.0f) ? 1 : 0;
    if (__any(need)) {
#pragma unroll
      for (int r = 0; r < 4; ++r) {
        const float mnew = fmaxf(Mrun[r], tmax[r]);
        const float alpha = exp2f(Mrun[r] - mnew);
        Mrun[r] = mnew;
        lrun[r] *= alpha;
#pragma unroll
        for (int no = 0; no < 8; ++no) oacc[no][r] *= alpha;
      }
    }

    float tsum[4];
#pragma unroll
    for (int r = 0; r < 4; ++r) tsum[r] = 0.f;
#pragma unroll
    for (int n = 0; n < 4; ++n)
#pragma unroll
      for (int r = 0; r < 4; ++r) {
        const float p = exp2f(sacc[n][r] - Mrun[r]);
        tsum[r] += p;
        const int prow = wid * 16 + orow + r;
        Ps[prow][sw8(prow, n * 16 + ocol)] = bf16bits(p);
      }
#pragma unroll
    for (int r = 0; r < 4; ++r) {
      float t = tsum[r];
      t += __shfl_xor(t, 1);
      t += __shfl_xor(t, 2);
      t += __shfl_xor(t, 4);
      t += __shfl_xor(t, 8);
      lrun[r] += t;
    }

    WAITLGKM();
    BARRIER();

    __builtin_amdgcn_s_setprio(1);
#pragma unroll
    for (int kk = 0; kk < 2; ++kk) {
      const int prow = wid * 16 + frow;
      bf16x8_t pa = *reinterpret_cast<const bf16x8_t*>(&Ps[prow][sw8(prow, kk * 32 + fk8)]);
#pragma unroll
      for (int no = 0; no < 8; ++no) {
        const int vrow = no * 16 + frow;
        bf16x8_t bv = *reinterpret_cast<const bf16x8_t*>(&Vs[cur][vrow][sw8(vrow, kk * 32 + fk8)]);
        oacc[no] = __builtin_amdgcn_mfma_f32_16x16x32_bf16(pa, bv, oacc[no], 0, 0, 0);
      }
    }
    __builtin_amdgcn_s_setprio(0);

    if (kt > 0) {
      asm volatile("s_waitcnt vmcnt(0)" ::: "memory");
      BARRIER();
      cur ^= 1;
    }
  }

#pragma unroll
  for (int r = 0; r < 4; ++r) {
    const float rl = 1.0f / lrun[r];
    const long trow = qrow0 + orow + r;
#pragma unroll
    for (int no = 0; no < 8; ++no)
      Out[trow * (long)D + h * Dh + no * 16 + ocol] = bf16bits(oacc[no][r] * rl);
  }
}

// ---- launch --------------------------------------------------------------

extern "C" void kernel_launch(void* const* d_in, const int* in_sizes, int n_in,
                              void* d_out, int out_size, void* d_ws, size_t ws_size,
                              hipStream_t stream) {
  const float* hs   = (const float*)d_in[0];
  const float* qkvw = (const float*)d_in[1];
  const float* ow   = (const float*)d_in[2];

  const int D = 2048, B = 2, H = 16;
  const long TD = (long)in_sizes[0];   // T*D = 8388608
  const long DD = (long)in_sizes[2];   // D*D = 4194304
  const int T = (int)(TD / D);         // 4096
  const int S = T / B;                 // 2048
  const int Dh = D / H;                // 128
  const float log2e = 1.44269504f;
  const float qs = (1.0f / sqrtf((float)Dh)) * log2e;  // Q prescale

  u16* ws  = (u16*)d_ws;
  u16* hsb = ws;                  // TD    (later reused as attn)
  u16* wt  = ws + TD;             // 3*DD  (qkv weights^T; +3DD = o-proj^T)
  u16* owt = wt + 3 * DD;         // DD
  u16* qkv = owt + DD;            // 3*TD  [Q | K | Vt]  (Vt fused in GEMM)
  u16* vt   = qkv + 2 * TD;       // Vt[bh][Dh][S] written by QKV epilogue
  u16* attn = hsb;                // TD    (overlay; hsb dead after QKV GEMM)

  // 1) hidden -> bf16
  k_cast_bf16<<<dim3((unsigned)(TD / 1024)), 256, 0, stream>>>(hs, hsb, TD);
  // 2) all weights: cast + transpose in one dispatch (z=0..2: qkvw, z=3: ow)
  k_transpose_cast4<<<dim3(D / 32, D / 32, 4), 256, 0, stream>>>(qkvw, ow, wt, D, D);
  // 3) fused QKV projection + V-transpose epilogue
  k_gemm8<u16><<<dim3((3 * D) / 256, T / 256), 512, 0, stream>>>(
      hsb, wt, qkv, T, 3 * D, D, TD, qs, vt);
  // 4) attention (QBLK=64, log2 domain, descending-k + defer-max + K/V dbuf)
  k_attn<<<dim3(S / 64, B * H), 256, 0, stream>>>(
      qkv, qkv + TD, vt, attn, B, S, H, D, log2e);
  // 5) output projection -> f32 d_out (128x256 tiles: 256 blocks = 1 round)
  k_gemm2<float><<<dim3(D / 256, T / 128), 512, 0, stream>>>(
      attn, owt, (float*)d_out, T, D, D, 0L, 1.0f);
}